// Round 3
// baseline (4410.044 us; speedup 1.0000x reference)
//
#include <hip/hip_runtime.h>
#include <math.h>

// ---- model constants ----
#define B_SZ    8
#define SEQ     4096
#define DMODEL  256
#define DIN     512     // d_inner
#define DSTATE  64
#define NH      8
#define HD      64
#define CONVDIM 640
#define DPROJ   1160
#define NCHUNK  32      // scan chunks per (b,h)
#define CLEN    128     // SEQ / NCHUNK

__device__ __forceinline__ float siluf(float v){ return v / (1.f + expf(-v)); }

// ---------------- encoder GEMM: h = x @ enc_w + enc_b ----------------
// 32 tokens per wg, thread = output column
__global__ __launch_bounds__(256) void enc_kernel(const float* __restrict__ x,
    const float* __restrict__ W, const float* __restrict__ bias, float* __restrict__ h)
{
  __shared__ float xl[32*64];
  const int tid = threadIdx.x;
  const long t0 = (long)blockIdx.x * 32;
  for (int i = tid; i < 32*64; i += 256) xl[i] = x[t0*64 + i];
  __syncthreads();
  float acc[32];
  const float bv = bias[tid];
  #pragma unroll
  for (int tok = 0; tok < 32; ++tok) acc[tok] = bv;
  for (int k = 0; k < 64; ++k) {
    const float wv = W[k*DMODEL + tid];
    #pragma unroll
    for (int tok = 0; tok < 32; ++tok) acc[tok] += xl[tok*64 + k] * wv;
  }
  #pragma unroll
  for (int tok = 0; tok < 32; ++tok) h[(t0 + tok)*DMODEL + tid] = acc[tok];
}

// ---------------- in_proj GEMM: (Mb x 256) @ (256 x 1160) ----------------
// 64x64 tile, BK=16, 256 thr, 4x4 micro-tile. Epilogue routes cols to z / xBC / dt(+softplus,dA).
__global__ __launch_bounds__(256) void inproj_kernel(const float* __restrict__ A,
    const float* __restrict__ W, float* __restrict__ zbuf, float* __restrict__ xbc,
    float* __restrict__ dtb, float* __restrict__ dab,
    const float* __restrict__ dt_bias, const float* __restrict__ A_log)
{
  __shared__ float As[16][68];
  __shared__ float Bs[16][68];
  const int tid = threadIdx.x;
  const int row0 = blockIdx.x * 64;
  const int col0 = blockIdx.y * 64;
  const int tx = tid & 15, ty = tid >> 4;
  const int am = tid >> 2, akq = tid & 3;   // A staging: 64 rows x (4 threads x float4)
  const int bk = tid >> 4, bc4 = tid & 15;  // B staging: 16 k-rows x (16 threads x float4)
  float acc[4][4] = {};
  for (int k0 = 0; k0 < 256; k0 += 16) {
    const float4 av = *(const float4*)(A + (long)(row0 + am)*256 + k0 + akq*4);
    As[akq*4+0][am] = av.x; As[akq*4+1][am] = av.y;
    As[akq*4+2][am] = av.z; As[akq*4+3][am] = av.w;
    const int gc = col0 + bc4*4;
    float4 bv = make_float4(0.f,0.f,0.f,0.f);
    if (gc < DPROJ) bv = *(const float4*)(W + (long)(k0 + bk)*DPROJ + gc); // 1160 % 4 == 0, rows 16B-aligned
    *(float4*)(&Bs[bk][bc4*4]) = bv;
    __syncthreads();
    #pragma unroll
    for (int kk = 0; kk < 16; ++kk) {
      const float4 a4 = *(const float4*)(&As[kk][ty*4]);
      const float4 b4 = *(const float4*)(&Bs[kk][tx*4]);
      const float ar[4] = {a4.x,a4.y,a4.z,a4.w};
      const float br[4] = {b4.x,b4.y,b4.z,b4.w};
      #pragma unroll
      for (int i=0;i<4;i++)
        #pragma unroll
        for (int j=0;j<4;j++) acc[i][j] += ar[i]*br[j];
    }
    __syncthreads();
  }
  #pragma unroll
  for (int i=0;i<4;i++){
    const long row = row0 + ty*4 + i;
    #pragma unroll
    for (int j=0;j<4;j++){
      const int col = col0 + tx*4 + j;
      const float v = acc[i][j];
      if (col < DIN) zbuf[row*DIN + col] = v;
      else if (col < DIN + CONVDIM) xbc[row*CONVDIM + (col - DIN)] = v;
      else if (col < DPROJ) {
        const int hh = col - (DIN + CONVDIM);
        const float dv = v + dt_bias[hh];
        const float sp = dv > 20.f ? dv : log1pf(expf(dv));   // softplus
        dtb[row*NH + hh] = sp;
        dab[row*NH + hh] = expf(sp * (-expf(A_log[hh])));     // dA = exp(dt*A), A = -exp(A_log)
      }
    }
  }
}

// ---------------- depthwise causal conv (width 4) + SiLU, split outputs ----------------
__global__ __launch_bounds__(256) void conv_kernel(const float* __restrict__ xbc,
    const float* __restrict__ cw, const float* __restrict__ cb,
    float* __restrict__ xs, float* __restrict__ Bb, float* __restrict__ Cb)
{
  const long idx = (long)blockIdx.x * 256 + threadIdx.x;   // Mb*640 total
  const int c = (int)(idx % CONVDIM);
  const long bt = idx / CONVDIM;
  const int t = (int)(bt & (SEQ-1));
  float acc = cb[c];
  #pragma unroll
  for (int k = 0; k < 4; ++k) {
    const int tt = t - 3 + k;
    if (tt >= 0) acc += xbc[(bt - 3 + k)*CONVDIM + c] * cw[c*4 + k];
  }
  acc = siluf(acc);
  if (c < DIN) xs[bt*DIN + c] = acc;
  else if (c < DIN + DSTATE) Bb[bt*DSTATE + (c - DIN)] = acc;
  else Cb[bt*DSTATE + (c - DIN - DSTATE)] = acc;
}

// ---------------- chunked SSD scan ----------------
// Phase A: per (b,h,chunk) local state from zero init + chunk decay product.
__global__ __launch_bounds__(64) void scanA_kernel(const float* __restrict__ xs,
    const float* __restrict__ Bb, const float* __restrict__ dab, const float* __restrict__ dtb,
    float* __restrict__ Sloc, float* __restrict__ Pb)
{
  const int wg = blockIdx.x;          // bh*NCHUNK + c
  const int c  = wg & (NCHUNK-1);
  const int bh = wg >> 5;
  const int hh = bh & (NH-1);
  const int b  = bh >> 3;             // batch index WITHIN group
  const int p  = threadIdx.x;
  float s[64];
  #pragma unroll
  for (int n=0;n<64;n++) s[n] = 0.f;
  float P = 1.f;
  const long bt0 = (long)b*SEQ + c*CLEN;
  for (int t = 0; t < CLEN; ++t) {
    const long bt = bt0 + t;
    const float dA  = dab[bt*NH + hh];
    const float dtv = dtb[bt*NH + hh];
    const float xp  = xs[bt*DIN + hh*HD + p];
    const float u = dtv * xp;
    const float* __restrict__ Brow = Bb + bt*DSTATE;
    #pragma unroll
    for (int n=0;n<64;n++) s[n] = s[n]*dA + u*Brow[n];
    P *= dA;
  }
  const long sb = (long)wg * 4096;    // layout [wg][n][p]
  #pragma unroll
  for (int n=0;n<64;n++) Sloc[sb + n*64 + p] = s[n];
  if (p == 0) Pb[wg] = P;
}

// Combine (in place): Sloc[c] := S_init[c]; run = P[c]*run + S_local[c]
__global__ __launch_bounds__(64) void scanMid_kernel(float* __restrict__ Sloc, const float* __restrict__ Pb)
{
  const int bh = blockIdx.x;
  const int p  = threadIdx.x;
  float run[64];
  #pragma unroll
  for (int n=0;n<64;n++) run[n] = 0.f;
  for (int c = 0; c < NCHUNK; ++c) {
    const long base = ((long)(bh*NCHUNK + c)) * 4096;
    const float Pc = Pb[bh*NCHUNK + c];
    #pragma unroll
    for (int n=0;n<64;n++) {
      const float tmp = Sloc[base + n*64 + p];
      Sloc[base + n*64 + p] = run[n];
      run[n] = run[n]*Pc + tmp;
    }
  }
}

// Phase C: replay chunk from S_init, emit y (+ Dp*x) IN PLACE over xs.
__global__ __launch_bounds__(64) void scanC_kernel(float* __restrict__ xs_y,
    const float* __restrict__ Bb, const float* __restrict__ Cb,
    const float* __restrict__ dab, const float* __restrict__ dtb,
    const float* __restrict__ Sinit, const float* __restrict__ Dp)
{
  const int wg = blockIdx.x;
  const int c  = wg & (NCHUNK-1);
  const int bh = wg >> 5;
  const int hh = bh & (NH-1);
  const int b  = bh >> 3;
  const int p  = threadIdx.x;
  float s[64];
  const long sb = (long)wg * 4096;
  #pragma unroll
  for (int n=0;n<64;n++) s[n] = Sinit[sb + n*64 + p];
  const float Dv = Dp[hh];
  const long bt0 = (long)b*SEQ + c*CLEN;
  for (int t = 0; t < CLEN; ++t) {
    const long bt = bt0 + t;
    const float dA  = dab[bt*NH + hh];
    const float dtv = dtb[bt*NH + hh];
    const float xp  = xs_y[bt*DIN + hh*HD + p];
    const float u = dtv * xp;
    const float* __restrict__ Brow = Bb + bt*DSTATE;
    const float* __restrict__ Crow = Cb + bt*DSTATE;
    float y0 = 0.f, y1 = 0.f;
    #pragma unroll
    for (int n=0;n<64;n+=2) {
      s[n]   = s[n]  *dA + u*Brow[n];   y0 += s[n]  *Crow[n];
      s[n+1] = s[n+1]*dA + u*Brow[n+1]; y1 += s[n+1]*Crow[n+1];
    }
    xs_y[bt*DIN + hh*HD + p] = y0 + y1 + Dv*xp;
  }
}

// ---------------- y*silu(z) + RMSNorm over DIN, in place over z ----------------
__global__ __launch_bounds__(256) void gnorm_kernel(const float* __restrict__ y,
    float* __restrict__ z_io, const float* __restrict__ nw)
{
  const long row = blockIdx.x;
  const int tid = threadIdx.x;
  float g[2];
  #pragma unroll
  for (int q=0;q<2;q++){
    const int cc = tid + q*256;
    const float yv = y[row*DIN + cc];
    const float zv = z_io[row*DIN + cc];
    g[q] = yv * siluf(zv);
  }
  float ss = g[0]*g[0] + g[1]*g[1];
  #pragma unroll
  for (int o=32;o;o>>=1) ss += __shfl_down(ss, o);
  __shared__ float red[4];
  if ((tid & 63) == 0) red[tid>>6] = ss;
  __syncthreads();
  const float tot = red[0]+red[1]+red[2]+red[3];
  const float scale = rsqrtf(tot * (1.f/512.f) + 1e-5f);
  #pragma unroll
  for (int q=0;q<2;q++){
    const int cc = tid + q*256;
    z_io[row*DIN + cc] = g[q] * scale * nw[cc];
  }
}

// ---------------- out_proj GEMM (K=512 -> 256) + residual add ----------------
__global__ __launch_bounds__(256) void outproj_kernel(const float* __restrict__ yn,
    const float* __restrict__ W, const float* __restrict__ resid, float* __restrict__ outb)
{
  __shared__ float ylds[32][65];
  const int tid = threadIdx.x;
  const long t0 = (long)blockIdx.x * 32;
  float acc[32] = {};
  for (int k0 = 0; k0 < 512; k0 += 64) {
    for (int i = tid; i < 32*64; i += 256) {
      const int tok = i >> 6, kk = i & 63;
      ylds[tok][kk] = yn[(t0 + tok)*DIN + k0 + kk];
    }
    __syncthreads();
    for (int kk = 0; kk < 64; ++kk) {
      const float wv = W[(long)(k0 + kk)*DMODEL + tid];
      #pragma unroll
      for (int tok = 0; tok < 32; ++tok) acc[tok] += ylds[tok][kk] * wv;
    }
    __syncthreads();
  }
  #pragma unroll
  for (int tok = 0; tok < 32; ++tok)
    outb[(t0+tok)*DMODEL + tid] = acc[tok] + resid[(t0+tok)*DMODEL + tid];
}

// ---------------- LayerNorm over DMODEL, wave per token ----------------
__global__ __launch_bounds__(256) void ln_kernel(const float* __restrict__ in,
    float* __restrict__ h, const float* __restrict__ w, const float* __restrict__ bb)
{
  const int lane = threadIdx.x & 63;
  const int wid  = threadIdx.x >> 6;
  const long row = (long)blockIdx.x * 4 + wid;
  const float* r = in + row*DMODEL;
  float v[4]; float sum = 0.f, sq = 0.f;
  #pragma unroll
  for (int q=0;q<4;q++){ v[q] = r[lane + q*64]; sum += v[q]; sq += v[q]*v[q]; }
  #pragma unroll
  for (int o=32;o;o>>=1){ sum += __shfl_xor(sum,o); sq += __shfl_xor(sq,o); }
  const float mu = sum * (1.f/256.f);
  const float var = sq * (1.f/256.f) - mu*mu;
  const float rs = rsqrtf(var + 1e-5f);
  #pragma unroll
  for (int q=0;q<4;q++){
    const int cc = lane + q*64;
    h[row*DMODEL + cc] = (v[q]-mu)*rs*w[cc] + bb[cc];
  }
}

// ---------------- decoder: h[:, -1, :] @ dec_w + dec_b  (fp32 output) ----------------
__global__ __launch_bounds__(64) void dec_kernel(const float* __restrict__ h,
    const float* __restrict__ W, const float* __restrict__ bias, float* __restrict__ out)
{
  const int wg = blockIdx.x;          // b_local*10 + o
  const int b = wg / 10, o = wg % 10;
  const int lane = threadIdx.x;
  const float* r = h + ((long)b*SEQ + SEQ-1)*DMODEL;
  float s = 0.f;
  #pragma unroll
  for (int q=0;q<4;q++){ const int k = lane + q*64; s += r[k]*W[k*10+o]; }
  #pragma unroll
  for (int o2=32;o2;o2>>=1) s += __shfl_down(s, o2);
  if (lane == 0) out[wg] = s + bias[o];
}

extern "C" void kernel_launch(void* const* d_in, const int* in_sizes, int n_in,
                              void* d_out, int out_size, void* d_ws, size_t ws_size,
                              hipStream_t stream) {
  const float* x        = (const float*)d_in[0];
  const float* enc_w    = (const float*)d_in[1];
  const float* enc_b    = (const float*)d_in[2];
  const float* in_proj  = (const float*)d_in[3];
  const float* conv_w   = (const float*)d_in[4];
  const float* conv_b   = (const float*)d_in[5];
  const float* dt_bias  = (const float*)d_in[6];
  const float* A_log    = (const float*)d_in[7];
  const float* Dp       = (const float*)d_in[8];
  const float* norm_w   = (const float*)d_in[9];
  const float* out_proj = (const float*)d_in[10];
  const float* ln_w     = (const float*)d_in[11];
  const float* ln_b     = (const float*)d_in[12];
  const float* dec_w    = (const float*)d_in[13];
  const float* dec_b    = (const float*)d_in[14];
  float* out = (float*)d_out;   // reference output dtype is float32

  // Batch-group size NB: largest in {8,4,2,1} whose workspace fits ws_size.
  // Per-token floats: h 256 + zbuf 512 + xbc 640 + xs 512 + Bb 64 + Cb 64 + dtb 8 + dab 8 = 2064
  // (Sloc = Mb*256 and tmp256 = Mb*256 alias the xbc region, which is dead after conv.)
  int NB = 8;
  while (NB > 1) {
    const long Mb = (long)NB * SEQ;
    const long bytes = (Mb * 2064L + 4096) * 4;
    if ((size_t)bytes <= ws_size) break;
    NB >>= 1;
  }
  const long Mb = (long)NB * SEQ;

  float* ws   = (float*)d_ws;
  float* h    = ws;                 // Mb*256
  float* zbuf = h    + Mb*DMODEL;   // Mb*512
  float* xbc  = zbuf + Mb*DIN;      // Mb*640 ; later aliased by Sloc (Mb*256) and tmp256 (Mb*256)
  float* xs   = xbc  + Mb*CONVDIM;  // Mb*512 ; y written in place by scanC
  float* Bb   = xs   + Mb*DIN;      // Mb*64
  float* Cb   = Bb   + Mb*DSTATE;   // Mb*64
  float* dtb  = Cb   + Mb*DSTATE;   // Mb*8
  float* dab  = dtb  + Mb*NH;       // Mb*8
  float* Pb   = dab  + Mb*NH;       // NB*8*32 <= 2048
  float* Sloc   = xbc;              // alias (xbc dead after conv): Mb*256 floats
  float* tmp256 = xbc;              // alias (Sloc dead after scanC): Mb*256 floats

  const int ngroups = B_SZ / NB;
  for (int g = 0; g < ngroups; ++g) {
    const float* xg = x + (long)g*NB*SEQ*64;

    enc_kernel<<<dim3((int)(Mb/32)), dim3(256), 0, stream>>>(xg, enc_w, enc_b, h);

    for (int l = 0; l < 2; ++l) {
      inproj_kernel<<<dim3((int)(Mb/64), 19), dim3(256), 0, stream>>>(
          h, in_proj + (long)l*256*DPROJ, zbuf, xbc, dtb, dab,
          dt_bias + l*NH, A_log + l*NH);
      conv_kernel<<<dim3((int)(Mb*CONVDIM/256)), dim3(256), 0, stream>>>(
          xbc, conv_w + (long)l*CONVDIM*4, conv_b + (long)l*CONVDIM, xs, Bb, Cb);
      scanA_kernel<<<dim3(NB*8*NCHUNK), dim3(64), 0, stream>>>(xs, Bb, dab, dtb, Sloc, Pb);
      scanMid_kernel<<<dim3(NB*8), dim3(64), 0, stream>>>(Sloc, Pb);
      scanC_kernel<<<dim3(NB*8*NCHUNK), dim3(64), 0, stream>>>(xs, Bb, Cb, dab, dtb, Sloc, Dp + l*NH);
      gnorm_kernel<<<dim3((int)Mb), dim3(256), 0, stream>>>(xs, zbuf, norm_w + (long)l*DIN);
      outproj_kernel<<<dim3((int)(Mb/32)), dim3(256), 0, stream>>>(
          zbuf, out_proj + (long)l*DIN*DMODEL, h, tmp256);
      ln_kernel<<<dim3((int)(Mb/4)), dim3(256), 0, stream>>>(tmp256, h, ln_w + l*DMODEL, ln_b + l*DMODEL);
    }

    dec_kernel<<<dim3(NB*10), dim3(64), 0, stream>>>(h, dec_w, dec_b, out + (long)g*NB*10);
  }
}

// Round 4
// 2045.082 us; speedup vs baseline: 2.1564x; 2.1564x over previous
//
#include <hip/hip_runtime.h>
#include <hip/hip_bf16.h>
#include <math.h>

// ---- model constants ----
#define B_SZ    8
#define SEQ     4096
#define DMODEL  256
#define DIN     512     // d_inner
#define DSTATE  64
#define NH      8
#define HD      64
#define CONVDIM 640
#define DPROJ   1160
#define NPAD    1216    // DPROJ padded to 19*64
#define NCHUNK  32      // scan chunks per (b,h)
#define CLEN    128     // SEQ / NCHUNK

typedef unsigned long long u64;
typedef unsigned short u16;
typedef __attribute__((ext_vector_type(8))) short bf16x8;
typedef __attribute__((ext_vector_type(4))) float f32x4;

__device__ __forceinline__ float siluf(float v){ return v / (1.f + expf(-v)); }
__device__ __forceinline__ u16 f2bf(float f){ __hip_bfloat16 h = __float2bfloat16(f); return *(u16*)&h; }

// ---------------- weight conversion (once per launch) ----------------
// in_proj_w [l][256 k][1160 n] fp32 -> Wt [l][1216 n][256 k] bf16 (zero-padded cols)
__global__ __launch_bounds__(256) void cvt_inw(const float* __restrict__ W, u16* __restrict__ Wt)
{
  const int blk = blockIdx.x;
  const int l = blk / NPAD, n = blk % NPAD;
  const int k = threadIdx.x;
  float v = 0.f;
  if (n < DPROJ) v = W[((long)l*DMODEL + k)*DPROJ + n];
  Wt[((long)l*NPAD + n)*DMODEL + k] = f2bf(v);
}

// out_proj_w [l][512 k][256 n] fp32 -> Wt [l][256 n][512 k] bf16
__global__ __launch_bounds__(256) void cvt_outw(const float* __restrict__ W, u16* __restrict__ Wt)
{
  const int blk = blockIdx.x;
  const int l = blk / DMODEL, n = blk % DMODEL;
  #pragma unroll
  for (int q = 0; q < 2; ++q) {
    const int k = threadIdx.x + q*256;
    const float v = W[((long)l*DIN + k)*DMODEL + n];
    Wt[((long)l*DMODEL + n)*DIN + k] = f2bf(v);
  }
}

// h fp32 (Mb x 256) -> hb bf16 compact
__global__ __launch_bounds__(256) void cvt_hb(const float* __restrict__ h, u16* __restrict__ hb)
{
  const long idx = (long)blockIdx.x*256 + threadIdx.x;
  const float4 v = ((const float4*)h)[idx];
  const u64 r = (u64)f2bf(v.x) | ((u64)f2bf(v.y)<<16) | ((u64)f2bf(v.z)<<32) | ((u64)f2bf(v.w)<<48);
  ((u64*)hb)[idx] = r;
}

// ---------------- encoder GEMM: h = x @ enc_w + enc_b ----------------
__global__ __launch_bounds__(256) void enc_kernel(const float* __restrict__ x,
    const float* __restrict__ W, const float* __restrict__ bias, float* __restrict__ h)
{
  __shared__ float xl[32*64];
  const int tid = threadIdx.x;
  const long t0 = (long)blockIdx.x * 32;
  for (int i = tid; i < 32*64; i += 256) xl[i] = x[t0*64 + i];
  __syncthreads();
  float acc[32];
  const float bv = bias[tid];
  #pragma unroll
  for (int tok = 0; tok < 32; ++tok) acc[tok] = bv;
  for (int k = 0; k < 64; ++k) {
    const float wv = W[k*DMODEL + tid];
    #pragma unroll
    for (int tok = 0; tok < 32; ++tok) acc[tok] += xl[tok*64 + k] * wv;
  }
  #pragma unroll
  for (int tok = 0; tok < 32; ++tok) h[(t0 + tok)*DMODEL + tid] = acc[tok];
}

// ---------------- in_proj MFMA GEMM: (Mb x 256)bf16 @ (256 x 1216)bf16 ----------------
// Tile 128x64, K-step 32, 4 waves; wave w: rows [w*32, w*32+32), all 64 cols.
// LDS rows padded to 36 shorts (72 B): conflict-light, 8B-aligned.
__global__ __launch_bounds__(256) void inproj_mfma(const u16* __restrict__ hb,
    const u16* __restrict__ Wt, float* __restrict__ zbuf, float* __restrict__ xbc,
    float* __restrict__ dtb, float* __restrict__ dab,
    const float* __restrict__ dt_bias, const float* __restrict__ A_log)
{
  __shared__ u16 Asl[128*36];
  __shared__ u16 Bsl[64*36];
  const int tid = threadIdx.x;
  const long m0 = (long)blockIdx.x * 128;
  const int n0 = blockIdx.y * 64;
  const int w = tid >> 6, lane = tid & 63;
  const int q = lane >> 4, l16 = lane & 15;
  const int arow = tid & 127, aseg = tid >> 7;   // A: 16 bf16 per thread
  const int brow = tid >> 2,  bseg = tid & 3;    // B: 8 bf16 per thread
  f32x4 acc[2][4] = {{{0.f,0.f,0.f,0.f}}};
  for (int k0 = 0; k0 < DMODEL; k0 += 32) {
    {
      const u64* src = (const u64*)(hb + (m0 + arow)*DMODEL + k0 + aseg*16);
      u64* dst = (u64*)(&Asl[arow*36 + aseg*16]);
      u64 x0=src[0], x1=src[1], x2=src[2], x3=src[3];
      dst[0]=x0; dst[1]=x1; dst[2]=x2; dst[3]=x3;
    }
    {
      const u64* src = (const u64*)(Wt + (long)(n0 + brow)*DMODEL + k0 + bseg*8);
      u64* dst = (u64*)(&Bsl[brow*36 + bseg*8]);
      u64 x0=src[0], x1=src[1];
      dst[0]=x0; dst[1]=x1;
    }
    __syncthreads();
    union U { u64 u[2]; bf16x8 v; };
    bf16x8 af[2], bfr[4];
    #pragma unroll
    for (int mi=0;mi<2;mi++){
      const u64* p = (const u64*)(&Asl[(w*32 + mi*16 + l16)*36 + q*8]);
      U t; t.u[0]=p[0]; t.u[1]=p[1]; af[mi]=t.v;
    }
    #pragma unroll
    for (int nj=0;nj<4;nj++){
      const u64* p = (const u64*)(&Bsl[(nj*16 + l16)*36 + q*8]);
      U t; t.u[0]=p[0]; t.u[1]=p[1]; bfr[nj]=t.v;
    }
    #pragma unroll
    for (int mi=0;mi<2;mi++)
      #pragma unroll
      for (int nj=0;nj<4;nj++)
        acc[mi][nj] = __builtin_amdgcn_mfma_f32_16x16x32_bf16(af[mi], bfr[nj], acc[mi][nj], 0,0,0);
    __syncthreads();
  }
  #pragma unroll
  for (int mi=0;mi<2;mi++){
    #pragma unroll
    for (int nj=0;nj<4;nj++){
      const int col = n0 + nj*16 + l16;
      #pragma unroll
      for (int r=0;r<4;r++){
        const long row = m0 + w*32 + mi*16 + q*4 + r;   // C/D: col=lane&15, row=quad*4+reg
        const float v = acc[mi][nj][r];
        if (col < DIN) zbuf[row*DIN + col] = v;
        else if (col < DIN + CONVDIM) xbc[row*CONVDIM + (col - DIN)] = v;
        else if (col < DPROJ) {
          const int hh = col - (DIN + CONVDIM);
          const float dv = v + dt_bias[hh];
          const float sp = dv > 20.f ? dv : log1pf(expf(dv));
          dtb[row*NH + hh] = sp;
          dab[row*NH + hh] = expf(sp * (-expf(A_log[hh])));
        }
      }
    }
  }
}

// ---------------- out_proj MFMA GEMM: (Mb x 512)bf16 @ (512 x 256)bf16 + residual ----------------
// A = gb, bf16 stored with row stride 1024 shorts (inside xs's fp32 rows).
__global__ __launch_bounds__(256) void outproj_mfma(const u16* __restrict__ gb,
    const u16* __restrict__ Wt, const float* __restrict__ resid, float* __restrict__ outb)
{
  __shared__ u16 Asl[128*36];
  __shared__ u16 Bsl[64*36];
  const int tid = threadIdx.x;
  const long m0 = (long)blockIdx.x * 128;
  const int n0 = blockIdx.y * 64;
  const int w = tid >> 6, lane = tid & 63;
  const int q = lane >> 4, l16 = lane & 15;
  const int arow = tid & 127, aseg = tid >> 7;
  const int brow = tid >> 2,  bseg = tid & 3;
  f32x4 acc[2][4] = {{{0.f,0.f,0.f,0.f}}};
  for (int k0 = 0; k0 < DIN; k0 += 32) {
    {
      const u64* src = (const u64*)(gb + (m0 + arow)*1024 + k0 + aseg*16);
      u64* dst = (u64*)(&Asl[arow*36 + aseg*16]);
      u64 x0=src[0], x1=src[1], x2=src[2], x3=src[3];
      dst[0]=x0; dst[1]=x1; dst[2]=x2; dst[3]=x3;
    }
    {
      const u64* src = (const u64*)(Wt + (long)(n0 + brow)*DIN + k0 + bseg*8);
      u64* dst = (u64*)(&Bsl[brow*36 + bseg*8]);
      u64 x0=src[0], x1=src[1];
      dst[0]=x0; dst[1]=x1;
    }
    __syncthreads();
    union U { u64 u[2]; bf16x8 v; };
    bf16x8 af[2], bfr[4];
    #pragma unroll
    for (int mi=0;mi<2;mi++){
      const u64* p = (const u64*)(&Asl[(w*32 + mi*16 + l16)*36 + q*8]);
      U t; t.u[0]=p[0]; t.u[1]=p[1]; af[mi]=t.v;
    }
    #pragma unroll
    for (int nj=0;nj<4;nj++){
      const u64* p = (const u64*)(&Bsl[(nj*16 + l16)*36 + q*8]);
      U t; t.u[0]=p[0]; t.u[1]=p[1]; bfr[nj]=t.v;
    }
    #pragma unroll
    for (int mi=0;mi<2;mi++)
      #pragma unroll
      for (int nj=0;nj<4;nj++)
        acc[mi][nj] = __builtin_amdgcn_mfma_f32_16x16x32_bf16(af[mi], bfr[nj], acc[mi][nj], 0,0,0);
    __syncthreads();
  }
  #pragma unroll
  for (int mi=0;mi<2;mi++){
    #pragma unroll
    for (int nj=0;nj<4;nj++){
      const int col = n0 + nj*16 + l16;
      #pragma unroll
      for (int r=0;r<4;r++){
        const long row = m0 + w*32 + mi*16 + q*4 + r;
        outb[row*DMODEL + col] = acc[mi][nj][r] + resid[row*DMODEL + col];
      }
    }
  }
}

// ---------------- depthwise causal conv (width 4) + SiLU, split outputs ----------------
__global__ __launch_bounds__(256) void conv_kernel(const float* __restrict__ xbc,
    const float* __restrict__ cw, const float* __restrict__ cb,
    float* __restrict__ xs, float* __restrict__ Bb, float* __restrict__ Cb)
{
  const long idx = (long)blockIdx.x * 256 + threadIdx.x;   // Mb*640 total
  const int c = (int)(idx % CONVDIM);
  const long bt = idx / CONVDIM;
  const int t = (int)(bt & (SEQ-1));
  float acc = cb[c];
  #pragma unroll
  for (int k = 0; k < 4; ++k) {
    const int tt = t - 3 + k;
    if (tt >= 0) acc += xbc[(bt - 3 + k)*CONVDIM + c] * cw[c*4 + k];
  }
  acc = siluf(acc);
  if (c < DIN) xs[bt*DIN + c] = acc;
  else if (c < DIN + DSTATE) Bb[bt*DSTATE + (c - DIN)] = acc;
  else Cb[bt*DSTATE + (c - DIN - DSTATE)] = acc;
}

// ---------------- chunked SSD scan ----------------
__global__ __launch_bounds__(64) void scanA_kernel(const float* __restrict__ xs,
    const float* __restrict__ Bb, const float* __restrict__ dab, const float* __restrict__ dtb,
    float* __restrict__ Sloc, float* __restrict__ Pb)
{
  const int wg = blockIdx.x;          // bh*NCHUNK + c
  const int c  = wg & (NCHUNK-1);
  const int bh = wg >> 5;
  const int hh = bh & (NH-1);
  const int b  = bh >> 3;
  const int p  = threadIdx.x;
  float s[64];
  #pragma unroll
  for (int n=0;n<64;n++) s[n] = 0.f;
  float P = 1.f;
  const long bt0 = (long)b*SEQ + c*CLEN;
  for (int t = 0; t < CLEN; ++t) {
    const long bt = bt0 + t;
    const float dA  = dab[bt*NH + hh];
    const float dtv = dtb[bt*NH + hh];
    const float xp  = xs[bt*DIN + hh*HD + p];
    const float u = dtv * xp;
    const float* __restrict__ Brow = Bb + bt*DSTATE;
    #pragma unroll
    for (int n=0;n<64;n++) s[n] = s[n]*dA + u*Brow[n];
    P *= dA;
  }
  const long sb = (long)wg * 4096;    // layout [wg][n][p]
  #pragma unroll
  for (int n=0;n<64;n++) Sloc[sb + n*64 + p] = s[n];
  if (p == 0) Pb[wg] = P;
}

// Parallel combine: one block per (bh, n); thread = p. run = P[c]*run + tmp across chunks.
__global__ __launch_bounds__(64) void scanMid_kernel(float* __restrict__ Sloc, const float* __restrict__ Pb)
{
  const int bh = blockIdx.x;
  const int n  = blockIdx.y;
  const int p  = threadIdx.x;
  float run = 0.f;
  for (int c = 0; c < NCHUNK; ++c) {
    const long base = ((long)(bh*NCHUNK + c))*4096 + n*64 + p;
    const float Pc = Pb[bh*NCHUNK + c];
    const float tmp = Sloc[base];
    Sloc[base] = run;
    run = run*Pc + tmp;
  }
}

// Phase C: replay chunk from S_init, emit y (+ Dp*x) IN PLACE over xs.
__global__ __launch_bounds__(64) void scanC_kernel(float* __restrict__ xs_y,
    const float* __restrict__ Bb, const float* __restrict__ Cb,
    const float* __restrict__ dab, const float* __restrict__ dtb,
    const float* __restrict__ Sinit, const float* __restrict__ Dp)
{
  const int wg = blockIdx.x;
  const int c  = wg & (NCHUNK-1);
  const int bh = wg >> 5;
  const int hh = bh & (NH-1);
  const int b  = bh >> 3;
  const int p  = threadIdx.x;
  float s[64];
  const long sb = (long)wg * 4096;
  #pragma unroll
  for (int n=0;n<64;n++) s[n] = Sinit[sb + n*64 + p];
  const float Dv = Dp[hh];
  const long bt0 = (long)b*SEQ + c*CLEN;
  for (int t = 0; t < CLEN; ++t) {
    const long bt = bt0 + t;
    const float dA  = dab[bt*NH + hh];
    const float dtv = dtb[bt*NH + hh];
    const float xp  = xs_y[bt*DIN + hh*HD + p];
    const float u = dtv * xp;
    const float* __restrict__ Brow = Bb + bt*DSTATE;
    const float* __restrict__ Crow = Cb + bt*DSTATE;
    float y0 = 0.f, y1 = 0.f;
    #pragma unroll
    for (int n=0;n<64;n+=2) {
      s[n]   = s[n]  *dA + u*Brow[n];   y0 += s[n]  *Crow[n];
      s[n+1] = s[n+1]*dA + u*Brow[n+1]; y1 += s[n+1]*Crow[n+1];
    }
    xs_y[bt*DIN + hh*HD + p] = y0 + y1 + Dv*xp;
  }
}

// ---------------- y*silu(z) + RMSNorm; emits bf16 A-operand (stride 1024 shorts) in place over xs ----------------
__global__ __launch_bounds__(256) void gnorm_kernel(float* __restrict__ y_io,
    const float* __restrict__ zb, const float* __restrict__ nw)
{
  const long row = blockIdx.x;
  const int tid = threadIdx.x;
  float g[2];
  #pragma unroll
  for (int q=0;q<2;q++){
    const int cc = tid + q*256;
    const float yv = y_io[row*DIN + cc];
    const float zv = zb[row*DIN + cc];
    g[q] = yv * siluf(zv);
  }
  float ss = g[0]*g[0] + g[1]*g[1];
  #pragma unroll
  for (int o=32;o;o>>=1) ss += __shfl_down(ss, o);
  __shared__ float red[4];
  if ((tid & 63) == 0) red[tid>>6] = ss;
  __syncthreads();   // also guarantees all reads of this row complete before bf16 overwrite
  const float tot = red[0]+red[1]+red[2]+red[3];
  const float scale = rsqrtf(tot * (1.f/512.f) + 1e-5f);
  u16* gp = (u16*)(y_io + row*DIN);
  #pragma unroll
  for (int q=0;q<2;q++){
    const int cc = tid + q*256;
    gp[cc] = f2bf(g[q] * scale * nw[cc]);
  }
}

// ---------------- LayerNorm over DMODEL, wave per token ----------------
__global__ __launch_bounds__(256) void ln_kernel(const float* __restrict__ in,
    float* __restrict__ h, const float* __restrict__ w, const float* __restrict__ bb)
{
  const int lane = threadIdx.x & 63;
  const int wid  = threadIdx.x >> 6;
  const long row = (long)blockIdx.x * 4 + wid;
  const float* r = in + row*DMODEL;
  float v[4]; float sum = 0.f, sq = 0.f;
  #pragma unroll
  for (int q=0;q<4;q++){ v[q] = r[lane + q*64]; sum += v[q]; sq += v[q]*v[q]; }
  #pragma unroll
  for (int o=32;o;o>>=1){ sum += __shfl_xor(sum,o); sq += __shfl_xor(sq,o); }
  const float mu = sum * (1.f/256.f);
  const float var = sq * (1.f/256.f) - mu*mu;
  const float rs = rsqrtf(var + 1e-5f);
  #pragma unroll
  for (int q=0;q<4;q++){
    const int cc = lane + q*64;
    h[row*DMODEL + cc] = (v[q]-mu)*rs*w[cc] + bb[cc];
  }
}

// ---------------- decoder: h[:, -1, :] @ dec_w + dec_b  (fp32 output) ----------------
__global__ __launch_bounds__(64) void dec_kernel(const float* __restrict__ h,
    const float* __restrict__ W, const float* __restrict__ bias, float* __restrict__ out)
{
  const int wg = blockIdx.x;
  const int b = wg / 10, o = wg % 10;
  const int lane = threadIdx.x;
  const float* r = h + ((long)b*SEQ + SEQ-1)*DMODEL;
  float s = 0.f;
  #pragma unroll
  for (int q=0;q<4;q++){ const int k = lane + q*64; s += r[k]*W[k*10+o]; }
  #pragma unroll
  for (int o2=32;o2;o2>>=1) s += __shfl_down(s, o2);
  if (lane == 0) out[wg] = s + bias[o];
}

extern "C" void kernel_launch(void* const* d_in, const int* in_sizes, int n_in,
                              void* d_out, int out_size, void* d_ws, size_t ws_size,
                              hipStream_t stream) {
  const float* x        = (const float*)d_in[0];
  const float* enc_w    = (const float*)d_in[1];
  const float* enc_b    = (const float*)d_in[2];
  const float* in_proj  = (const float*)d_in[3];
  const float* conv_w   = (const float*)d_in[4];
  const float* conv_b   = (const float*)d_in[5];
  const float* dt_bias  = (const float*)d_in[6];
  const float* A_log    = (const float*)d_in[7];
  const float* Dp       = (const float*)d_in[8];
  const float* norm_w   = (const float*)d_in[9];
  const float* out_proj = (const float*)d_in[10];
  const float* ln_w     = (const float*)d_in[11];
  const float* ln_b     = (const float*)d_in[12];
  const float* dec_w    = (const float*)d_in[13];
  const float* dec_b    = (const float*)d_in[14];
  float* out = (float*)d_out;

  // ws layout: bf16 weights first (group-independent), then per-group fp32 buffers.
  // WtIn: 2*1216*256 bf16 = 311296 fl-eq; WtOut: 2*256*512 bf16 = 131072 fl-eq.
  float* ws = (float*)d_ws;
  u16* WtIn  = (u16*)ws;                       // 622592 shorts
  u16* WtOut = WtIn + (long)2*NPAD*DMODEL;     // 262144 shorts
  float* gbase = ws + 311296 + 131072;         // per-group region

  // Per-token floats: h 256 + zbuf 512 + xbc 640 + xs 512 + Bb 64 + Cb 64 + dtb 8 + dab 8 = 2064
  int NB = 8;
  while (NB > 1) {
    const long Mb = (long)NB * SEQ;
    const long bytes = (442368L + Mb * 2064L + 4096) * 4;
    if ((size_t)bytes <= ws_size) break;
    NB >>= 1;
  }
  const long Mb = (long)NB * SEQ;

  float* h    = gbase;              // Mb*256
  float* zbuf = h    + Mb*DMODEL;   // Mb*512
  float* xbc  = zbuf + Mb*DIN;      // Mb*640 ; aliased later by Sloc / tmp256
  float* xs   = xbc  + Mb*CONVDIM;  // Mb*512 ; holds hb(bf16), then conv x, then y, then gb(bf16)
  float* Bb   = xs   + Mb*DIN;      // Mb*64
  float* Cb   = Bb   + Mb*DSTATE;   // Mb*64
  float* dtb  = Cb   + Mb*DSTATE;   // Mb*8
  float* dab  = dtb  + Mb*NH;       // Mb*8
  float* Pb   = dab  + Mb*NH;       // <= 2048
  float* Sloc   = xbc;              // alias: Mb*256 floats (xbc dead after conv)
  float* tmp256 = xbc;              // alias: Mb*256 floats (Sloc dead after scanC)

  cvt_inw <<<dim3(2*NPAD),   dim3(256), 0, stream>>>(in_proj,  WtIn);
  cvt_outw<<<dim3(2*DMODEL), dim3(256), 0, stream>>>(out_proj, WtOut);

  const int ngroups = B_SZ / NB;
  for (int g = 0; g < ngroups; ++g) {
    const float* xg = x + (long)g*NB*SEQ*64;

    enc_kernel<<<dim3((int)(Mb/32)), dim3(256), 0, stream>>>(xg, enc_w, enc_b, h);

    for (int l = 0; l < 2; ++l) {
      cvt_hb<<<dim3((int)(Mb/4)), dim3(256), 0, stream>>>(h, (u16*)xs);
      inproj_mfma<<<dim3((int)(Mb/128), NPAD/64), dim3(256), 0, stream>>>(
          (u16*)xs, WtIn + (long)l*NPAD*DMODEL, zbuf, xbc, dtb, dab,
          dt_bias + l*NH, A_log + l*NH);
      conv_kernel<<<dim3((int)(Mb*CONVDIM/256)), dim3(256), 0, stream>>>(
          xbc, conv_w + (long)l*CONVDIM*4, conv_b + (long)l*CONVDIM, xs, Bb, Cb);
      scanA_kernel<<<dim3(NB*8*NCHUNK), dim3(64), 0, stream>>>(xs, Bb, dab, dtb, Sloc, Pb);
      scanMid_kernel<<<dim3(NB*8, 64), dim3(64), 0, stream>>>(Sloc, Pb);
      scanC_kernel<<<dim3(NB*8*NCHUNK), dim3(64), 0, stream>>>(xs, Bb, Cb, dab, dtb, Sloc, Dp + l*NH);
      gnorm_kernel<<<dim3((int)Mb), dim3(256), 0, stream>>>(xs, zbuf, norm_w + (long)l*DIN);
      outproj_mfma<<<dim3((int)(Mb/128), 4), dim3(256), 0, stream>>>(
          (u16*)xs, WtOut + (long)l*DMODEL*DIN, h, tmp256);
      ln_kernel<<<dim3((int)(Mb/4)), dim3(256), 0, stream>>>(tmp256, h, ln_w + l*DMODEL, ln_b + l*DMODEL);
    }

    dec_kernel<<<dim3(NB*10), dim3(64), 0, stream>>>(h, dec_w, dec_b, out + (long)g*NB*10);
  }
}

// Round 5
// 852.642 us; speedup vs baseline: 5.1722x; 2.3985x over previous
//
#include <hip/hip_runtime.h>
#include <hip/hip_bf16.h>
#include <math.h>

// ---- model constants ----
#define B_SZ    8
#define SEQ     4096
#define DMODEL  256
#define DIN     512     // d_inner
#define DSTATE  64
#define NH      8
#define HD      64
#define CONVDIM 640
#define DPROJ   1160
#define NPAD    1216    // DPROJ padded to 19*64
#define NCHUNK  32      // scan chunks per (b,h)
#define CLEN    128     // SEQ / NCHUNK
#define STR64   68      // LDS row stride (shorts) for K=64 tiles: 136 B, bank +2/row
#define STR128  132     // LDS row stride (shorts) for K=128 tiles: 264 B, bank +2/row

typedef unsigned long long u64;
typedef unsigned short u16;
typedef __attribute__((ext_vector_type(8))) short bf16x8;
typedef __attribute__((ext_vector_type(4))) float f32x4;

__device__ __forceinline__ float siluf(float v){ return v / (1.f + expf(-v)); }
__device__ __forceinline__ u16 f2bf(float f){ __hip_bfloat16 h = __float2bfloat16(f); return *(u16*)&h; }
__device__ __forceinline__ bf16x8 ldfrag(const u16* base){
  union { u64 u[2]; bf16x8 v; } t;
  const u64* p = (const u64*)base;
  t.u[0] = p[0]; t.u[1] = p[1];
  return t.v;
}

// ---------------- weight conversion (once per launch) ----------------
__global__ __launch_bounds__(256) void cvt_inw(const float* __restrict__ W, u16* __restrict__ Wt)
{
  const int blk = blockIdx.x;
  const int l = blk / NPAD, n = blk % NPAD;
  const int k = threadIdx.x;
  float v = 0.f;
  if (n < DPROJ) v = W[((long)l*DMODEL + k)*DPROJ + n];
  Wt[((long)l*NPAD + n)*DMODEL + k] = f2bf(v);
}

__global__ __launch_bounds__(256) void cvt_outw(const float* __restrict__ W, u16* __restrict__ Wt)
{
  const int blk = blockIdx.x;
  const int l = blk / DMODEL, n = blk % DMODEL;
  #pragma unroll
  for (int q = 0; q < 2; ++q) {
    const int k = threadIdx.x + q*256;
    const float v = W[((long)l*DIN + k)*DMODEL + n];
    Wt[((long)l*DMODEL + n)*DIN + k] = f2bf(v);
  }
}

__global__ __launch_bounds__(256) void cvt_hb(const float* __restrict__ h, u16* __restrict__ hb)
{
  const long idx = (long)blockIdx.x*256 + threadIdx.x;
  const float4 v = ((const float4*)h)[idx];
  const u64 r = (u64)f2bf(v.x) | ((u64)f2bf(v.y)<<16) | ((u64)f2bf(v.z)<<32) | ((u64)f2bf(v.w)<<48);
  ((u64*)hb)[idx] = r;
}

// ---------------- encoder GEMM ----------------
__global__ __launch_bounds__(256) void enc_kernel(const float* __restrict__ x,
    const float* __restrict__ W, const float* __restrict__ bias, float* __restrict__ h)
{
  __shared__ float xl[32*64];
  const int tid = threadIdx.x;
  const long t0 = (long)blockIdx.x * 32;
  for (int i = tid; i < 32*64; i += 256) xl[i] = x[t0*64 + i];
  __syncthreads();
  float acc[32];
  const float bv = bias[tid];
  #pragma unroll
  for (int tok = 0; tok < 32; ++tok) acc[tok] = bv;
  for (int k = 0; k < 64; ++k) {
    const float wv = W[k*DMODEL + tid];
    #pragma unroll
    for (int tok = 0; tok < 32; ++tok) acc[tok] += xl[tok*64 + k] * wv;
  }
  #pragma unroll
  for (int tok = 0; tok < 32; ++tok) h[(t0 + tok)*DMODEL + tid] = acc[tok];
}

// ---------------- in_proj MFMA GEMM; epilogue stores dt(softplus) and LOG dA ----------------
__global__ __launch_bounds__(256) void inproj_mfma(const u16* __restrict__ hb,
    const u16* __restrict__ Wt, float* __restrict__ zbuf, float* __restrict__ xbc,
    float* __restrict__ dtb, float* __restrict__ lab,
    const float* __restrict__ dt_bias, const float* __restrict__ A_log)
{
  __shared__ u16 Asl[128*36];
  __shared__ u16 Bsl[64*36];
  const int tid = threadIdx.x;
  const long m0 = (long)blockIdx.x * 128;
  const int n0 = blockIdx.y * 64;
  const int w = tid >> 6, lane = tid & 63;
  const int q = lane >> 4, l16 = lane & 15;
  const int arow = tid & 127, aseg = tid >> 7;
  const int brow = tid >> 2,  bseg = tid & 3;
  f32x4 acc[2][4] = {{{0.f,0.f,0.f,0.f}}};
  for (int k0 = 0; k0 < DMODEL; k0 += 32) {
    {
      const u64* src = (const u64*)(hb + (m0 + arow)*DMODEL + k0 + aseg*16);
      u64* dst = (u64*)(&Asl[arow*36 + aseg*16]);
      u64 x0=src[0], x1=src[1], x2=src[2], x3=src[3];
      dst[0]=x0; dst[1]=x1; dst[2]=x2; dst[3]=x3;
    }
    {
      const u64* src = (const u64*)(Wt + (long)(n0 + brow)*DMODEL + k0 + bseg*8);
      u64* dst = (u64*)(&Bsl[brow*36 + bseg*8]);
      u64 x0=src[0], x1=src[1];
      dst[0]=x0; dst[1]=x1;
    }
    __syncthreads();
    bf16x8 af[2], bfr[4];
    #pragma unroll
    for (int mi=0;mi<2;mi++) af[mi] = ldfrag(&Asl[(w*32 + mi*16 + l16)*36 + q*8]);
    #pragma unroll
    for (int nj=0;nj<4;nj++) bfr[nj] = ldfrag(&Bsl[(nj*16 + l16)*36 + q*8]);
    #pragma unroll
    for (int mi=0;mi<2;mi++)
      #pragma unroll
      for (int nj=0;nj<4;nj++)
        acc[mi][nj] = __builtin_amdgcn_mfma_f32_16x16x32_bf16(af[mi], bfr[nj], acc[mi][nj], 0,0,0);
    __syncthreads();
  }
  #pragma unroll
  for (int mi=0;mi<2;mi++){
    #pragma unroll
    for (int nj=0;nj<4;nj++){
      const int col = n0 + nj*16 + l16;
      #pragma unroll
      for (int r=0;r<4;r++){
        const long row = m0 + w*32 + mi*16 + q*4 + r;
        const float v = acc[mi][nj][r];
        if (col < DIN) zbuf[row*DIN + col] = v;
        else if (col < DIN + CONVDIM) xbc[row*CONVDIM + (col - DIN)] = v;
        else if (col < DPROJ) {
          const int hh = col - (DIN + CONVDIM);
          const float dv = v + dt_bias[hh];
          const float sp = dv > 20.f ? dv : log1pf(expf(dv));
          dtb[row*NH + hh] = sp;
          lab[row*NH + hh] = sp * (-expf(A_log[hh]));   // log dA
        }
      }
    }
  }
}

// ---------------- out_proj MFMA GEMM + residual ----------------
__global__ __launch_bounds__(256) void outproj_mfma(const u16* __restrict__ gb,
    const u16* __restrict__ Wt, const float* __restrict__ resid, float* __restrict__ outb)
{
  __shared__ u16 Asl[128*36];
  __shared__ u16 Bsl[64*36];
  const int tid = threadIdx.x;
  const long m0 = (long)blockIdx.x * 128;
  const int n0 = blockIdx.y * 64;
  const int w = tid >> 6, lane = tid & 63;
  const int q = lane >> 4, l16 = lane & 15;
  const int arow = tid & 127, aseg = tid >> 7;
  const int brow = tid >> 2,  bseg = tid & 3;
  f32x4 acc[2][4] = {{{0.f,0.f,0.f,0.f}}};
  for (int k0 = 0; k0 < DIN; k0 += 32) {
    {
      const u64* src = (const u64*)(gb + (m0 + arow)*1024 + k0 + aseg*16);
      u64* dst = (u64*)(&Asl[arow*36 + aseg*16]);
      u64 x0=src[0], x1=src[1], x2=src[2], x3=src[3];
      dst[0]=x0; dst[1]=x1; dst[2]=x2; dst[3]=x3;
    }
    {
      const u64* src = (const u64*)(Wt + (long)(n0 + brow)*DIN + k0 + bseg*8);
      u64* dst = (u64*)(&Bsl[brow*36 + bseg*8]);
      u64 x0=src[0], x1=src[1];
      dst[0]=x0; dst[1]=x1;
    }
    __syncthreads();
    bf16x8 af[2], bfr[4];
    #pragma unroll
    for (int mi=0;mi<2;mi++) af[mi] = ldfrag(&Asl[(w*32 + mi*16 + l16)*36 + q*8]);
    #pragma unroll
    for (int nj=0;nj<4;nj++) bfr[nj] = ldfrag(&Bsl[(nj*16 + l16)*36 + q*8]);
    #pragma unroll
    for (int mi=0;mi<2;mi++)
      #pragma unroll
      for (int nj=0;nj<4;nj++)
        acc[mi][nj] = __builtin_amdgcn_mfma_f32_16x16x32_bf16(af[mi], bfr[nj], acc[mi][nj], 0,0,0);
    __syncthreads();
  }
  #pragma unroll
  for (int mi=0;mi<2;mi++){
    #pragma unroll
    for (int nj=0;nj<4;nj++){
      const int col = n0 + nj*16 + l16;
      #pragma unroll
      for (int r=0;r<4;r++){
        const long row = m0 + w*32 + mi*16 + q*4 + r;
        outb[row*DMODEL + col] = acc[mi][nj][r] + resid[row*DMODEL + col];
      }
    }
  }
}

// ---------------- depthwise causal conv + SiLU ----------------
__global__ __launch_bounds__(256) void conv_kernel(const float* __restrict__ xbc,
    const float* __restrict__ cw, const float* __restrict__ cb,
    float* __restrict__ xs, float* __restrict__ Bb, float* __restrict__ Cb)
{
  const long idx = (long)blockIdx.x * 256 + threadIdx.x;
  const int c = (int)(idx % CONVDIM);
  const long bt = idx / CONVDIM;
  const int t = (int)(bt & (SEQ-1));
  float acc = cb[c];
  #pragma unroll
  for (int k = 0; k < 4; ++k) {
    const int tt = t - 3 + k;
    if (tt >= 0) acc += xbc[(bt - 3 + k)*CONVDIM + c] * cw[c*4 + k];
  }
  acc = siluf(acc);
  if (c < DIN) xs[bt*DIN + c] = acc;
  else if (c < DIN + DSTATE) Bb[bt*DSTATE + (c - DIN)] = acc;
  else Cb[bt*DSTATE + (c - DIN - DSTATE)] = acc;
}

// ---------------- SSD phase A: per chunk-head local state via MFMA ----------------
// S_local[p][n] = sum_s (dt[s]*exp(cum[127]-cum[s])*x[s][p]) * B[s][n];  P = exp(cum[127])
__global__ __launch_bounds__(256) void scanS_kernel(const float* __restrict__ xs,
    const float* __restrict__ Bb, const float* __restrict__ lab, const float* __restrict__ dtb,
    float* __restrict__ Sloc, float* __restrict__ Pb)
{
  __shared__ __align__(16) u16 Btr[64*STR128];   // [n][s]
  __shared__ __align__(16) u16 Uw[64*STR128];    // [p][s]  (weighted U, transposed)
  __shared__ float cexpL[128];
  const int wg = blockIdx.x;
  const int c = wg & (NCHUNK-1), bh = wg >> 5, hh = bh & (NH-1), b = bh >> 3;
  const int tid = threadIdx.x;
  const long bt0 = (long)b*SEQ + c*CLEN;
  if (tid < 64) {   // wave 0: inclusive prefix of log dA over 128 steps
    float a0 = lab[(bt0+tid)*NH + hh];
    float a1 = lab[(bt0+64+tid)*NH + hh];
    const float d0 = dtb[(bt0+tid)*NH + hh];
    const float d1 = dtb[(bt0+64+tid)*NH + hh];
    #pragma unroll
    for (int o=1;o<64;o<<=1){
      const float t0=__shfl_up(a0,o), t1=__shfl_up(a1,o);
      if (tid>=o){a0+=t0;a1+=t1;}
    }
    a1 += __shfl(a0,63);
    const float ctot = __shfl(a1,63);
    cexpL[tid]    = d0*__expf(ctot - a0);
    cexpL[tid+64] = d1*__expf(ctot - a1);
    if (tid==0) Pb[wg] = __expf(ctot);
  }
  __syncthreads();
  {
    const int v = tid & 63, r0 = tid >> 6;
    #pragma unroll 4
    for (int k=0;k<32;k++){
      const int s = r0 + k*4;
      Btr[v*STR128 + s] = f2bf(Bb[(bt0+s)*DSTATE + v]);
      Uw[v*STR128 + s]  = f2bf(cexpL[s]*xs[(bt0+s)*DIN + hh*HD + v]);
    }
  }
  __syncthreads();
  const int w = tid>>6, lane = tid&63, q = lane>>4, l16 = lane&15;
  f32x4 acc[4] = {};
  #pragma unroll
  for (int ks=0;ks<4;ks++){
    const bf16x8 af = ldfrag(&Uw[(w*16+l16)*STR128 + ks*32 + q*8]);
    #pragma unroll
    for (int nj=0;nj<4;nj++){
      const bf16x8 bf = ldfrag(&Btr[(nj*16+l16)*STR128 + ks*32 + q*8]);
      acc[nj] = __builtin_amdgcn_mfma_f32_16x16x32_bf16(af, bf, acc[nj], 0,0,0);
    }
  }
  const long sb = (long)wg*4096;   // [wg][p][n]
  #pragma unroll
  for (int nj=0;nj<4;nj++)
    #pragma unroll
    for (int r=0;r<4;r++)
      Sloc[sb + (w*16+q*4+r)*64 + nj*16 + l16] = acc[nj][r];
}

// Parallel combine (elementwise over the 4096-state): Sloc[c] := running; run = P[c]*run + tmp
__global__ __launch_bounds__(64) void scanMid_kernel(float* __restrict__ Sloc, const float* __restrict__ Pb)
{
  const int bh = blockIdx.x;
  const int rr = blockIdx.y;
  const int p  = threadIdx.x;
  float run = 0.f;
  for (int c = 0; c < NCHUNK; ++c) {
    const long base = ((long)(bh*NCHUNK + c))*4096 + rr*64 + p;
    const float Pc = Pb[bh*NCHUNK + c];
    const float tmp = Sloc[base];
    Sloc[base] = run;
    run = run*Pc + tmp;
  }
}

// ---------------- SSD phase C: Y = ((C Bt) o L) U + diag(exp(cum)) (C h0) + D*x, via MFMA ----------------
__global__ __launch_bounds__(512) void scanY_kernel(float* __restrict__ xs_y,
    const float* __restrict__ Bb, const float* __restrict__ Cb,
    const float* __restrict__ lab, const float* __restrict__ dtb,
    const float* __restrict__ Sinit, const float* __restrict__ Dp)
{
  __shared__ __align__(16) u16 pool[2*128*STR64];  // Bs[s][n] | Cs[t][n]; later overlaid by Ms[t][s]
  __shared__ __align__(16) u16 Ut[64*STR128];      // [p][s]
  __shared__ __align__(16) u16 h0t[64*STR64];      // [p][n]
  __shared__ float cumL[128];
  __shared__ float dtL[128];
  u16* Bs = pool;
  u16* Cs = pool + 128*STR64;
  u16* Ms = pool;                                  // overlay after Bs/Cs are dead

  const int wg = blockIdx.x;
  const int c = wg & (NCHUNK-1), bh = wg >> 5, hh = bh & (NH-1), b = bh >> 3;
  const int tid = threadIdx.x;
  const long bt0 = (long)b*SEQ + c*CLEN;

  if (tid < 64) {
    float a0 = lab[(bt0+tid)*NH + hh];
    float a1 = lab[(bt0+64+tid)*NH + hh];
    dtL[tid]    = dtb[(bt0+tid)*NH + hh];
    dtL[tid+64] = dtb[(bt0+64+tid)*NH + hh];
    #pragma unroll
    for (int o=1;o<64;o<<=1){
      const float t0=__shfl_up(a0,o), t1=__shfl_up(a1,o);
      if (tid>=o){a0+=t0;a1+=t1;}
    }
    a1 += __shfl(a0,63);
    cumL[tid]=a0; cumL[tid+64]=a1;
  }
  __syncthreads();
  {
    const int n = tid & 63, r0 = tid >> 6;   // 512 threads: r0 in 0..7
    #pragma unroll 4
    for (int k=0;k<16;k++){
      const int s = r0 + k*8;
      Bs[s*STR64 + n] = f2bf(Bb[(bt0+s)*DSTATE + n]);
      Cs[s*STR64 + n] = f2bf(Cb[(bt0+s)*DSTATE + n]);
      Ut[n*STR128 + s] = f2bf(dtL[s]*xs_y[(bt0+s)*DIN + hh*HD + n]);
    }
    const int n0 = r0*8;
    const float* hp = Sinit + (long)wg*4096 + n*64 + n0;
    #pragma unroll
    for (int j=0;j<8;j++) h0t[n*STR64 + n0 + j] = f2bf(hp[j]);
  }
  __syncthreads();

  const int w = tid>>6, lane = tid&63, q = lane>>4, l16 = lane&15;  // wave w handles t in [16w,16w+16)
  f32x4 accG[8] = {};   // G[t][s] tiles
  f32x4 accI[4] = {};   // (C @ h0)[t][p] tiles
  #pragma unroll
  for (int ks=0;ks<2;ks++){
    const bf16x8 af = ldfrag(&Cs[(w*16+l16)*STR64 + ks*32 + q*8]);
    #pragma unroll
    for (int nj=0;nj<8;nj++)
      accG[nj] = __builtin_amdgcn_mfma_f32_16x16x32_bf16(af, ldfrag(&Bs[(nj*16+l16)*STR64 + ks*32 + q*8]), accG[nj], 0,0,0);
    #pragma unroll
    for (int nj=0;nj<4;nj++)
      accI[nj] = __builtin_amdgcn_mfma_f32_16x16x32_bf16(af, ldfrag(&h0t[(nj*16+l16)*STR64 + ks*32 + q*8]), accI[nj], 0,0,0);
  }
  __syncthreads();   // everyone done reading Bs/Cs before Ms overlay is written
  #pragma unroll
  for (int nj=0;nj<8;nj++){
    const int s = nj*16 + l16;
    #pragma unroll
    for (int r=0;r<4;r++){
      const int t = w*16 + q*4 + r;
      const float v = (s<=t) ? accG[nj][r]*__expf(cumL[t]-cumL[s]) : 0.f;
      Ms[t*STR128 + s] = f2bf(v);
    }
  }
  __syncthreads();
  f32x4 accY[4] = {};
  #pragma unroll
  for (int ks=0;ks<4;ks++){
    const bf16x8 af = ldfrag(&Ms[(w*16+l16)*STR128 + ks*32 + q*8]);
    #pragma unroll
    for (int nj=0;nj<4;nj++)
      accY[nj] = __builtin_amdgcn_mfma_f32_16x16x32_bf16(af, ldfrag(&Ut[(nj*16+l16)*STR128 + ks*32 + q*8]), accY[nj], 0,0,0);
  }
  const float Dv = Dp[hh];
  #pragma unroll
  for (int nj=0;nj<4;nj++){
    const int p = nj*16 + l16;
    #pragma unroll
    for (int r=0;r<4;r++){
      const int t = w*16 + q*4 + r;
      const long a = (bt0+t)*DIN + hh*HD + p;
      const float xv = xs_y[a];
      xs_y[a] = accY[nj][r] + __expf(cumL[t])*accI[nj][r] + Dv*xv;
    }
  }
}

// ---------------- y*silu(z) + RMSNorm; emits bf16 A-operand in place over xs ----------------
__global__ __launch_bounds__(256) void gnorm_kernel(float* __restrict__ y_io,
    const float* __restrict__ zb, const float* __restrict__ nw)
{
  const long row = blockIdx.x;
  const int tid = threadIdx.x;
  float g[2];
  #pragma unroll
  for (int q=0;q<2;q++){
    const int cc = tid + q*256;
    const float yv = y_io[row*DIN + cc];
    const float zv = zb[row*DIN + cc];
    g[q] = yv * siluf(zv);
  }
  float ss = g[0]*g[0] + g[1]*g[1];
  #pragma unroll
  for (int o=32;o;o>>=1) ss += __shfl_down(ss, o);
  __shared__ float red[4];
  if ((tid & 63) == 0) red[tid>>6] = ss;
  __syncthreads();
  const float tot = red[0]+red[1]+red[2]+red[3];
  const float scale = rsqrtf(tot * (1.f/512.f) + 1e-5f);
  u16* gp = (u16*)(y_io + row*DIN);
  #pragma unroll
  for (int q=0;q<2;q++){
    const int cc = tid + q*256;
    gp[cc] = f2bf(g[q] * scale * nw[cc]);
  }
}

// ---------------- LayerNorm ----------------
__global__ __launch_bounds__(256) void ln_kernel(const float* __restrict__ in,
    float* __restrict__ h, const float* __restrict__ w, const float* __restrict__ bb)
{
  const int lane = threadIdx.x & 63;
  const int wid  = threadIdx.x >> 6;
  const long row = (long)blockIdx.x * 4 + wid;
  const float* r = in + row*DMODEL;
  float v[4]; float sum = 0.f, sq = 0.f;
  #pragma unroll
  for (int q=0;q<4;q++){ v[q] = r[lane + q*64]; sum += v[q]; sq += v[q]*v[q]; }
  #pragma unroll
  for (int o=32;o;o>>=1){ sum += __shfl_xor(sum,o); sq += __shfl_xor(sq,o); }
  const float mu = sum * (1.f/256.f);
  const float var = sq * (1.f/256.f) - mu*mu;
  const float rs = rsqrtf(var + 1e-5f);
  #pragma unroll
  for (int q=0;q<4;q++){
    const int cc = lane + q*64;
    h[row*DMODEL + cc] = (v[q]-mu)*rs*w[cc] + bb[cc];
  }
}

// ---------------- decoder (fp32 output) ----------------
__global__ __launch_bounds__(64) void dec_kernel(const float* __restrict__ h,
    const float* __restrict__ W, const float* __restrict__ bias, float* __restrict__ out)
{
  const int wg = blockIdx.x;
  const int b = wg / 10, o = wg % 10;
  const int lane = threadIdx.x;
  const float* r = h + ((long)b*SEQ + SEQ-1)*DMODEL;
  float s = 0.f;
  #pragma unroll
  for (int q=0;q<4;q++){ const int k = lane + q*64; s += r[k]*W[k*10+o]; }
  #pragma unroll
  for (int o2=32;o2;o2>>=1) s += __shfl_down(s, o2);
  if (lane == 0) out[wg] = s + bias[o];
}

extern "C" void kernel_launch(void* const* d_in, const int* in_sizes, int n_in,
                              void* d_out, int out_size, void* d_ws, size_t ws_size,
                              hipStream_t stream) {
  const float* x        = (const float*)d_in[0];
  const float* enc_w    = (const float*)d_in[1];
  const float* enc_b    = (const float*)d_in[2];
  const float* in_proj  = (const float*)d_in[3];
  const float* conv_w   = (const float*)d_in[4];
  const float* conv_b   = (const float*)d_in[5];
  const float* dt_bias  = (const float*)d_in[6];
  const float* A_log    = (const float*)d_in[7];
  const float* Dp       = (const float*)d_in[8];
  const float* norm_w   = (const float*)d_in[9];
  const float* out_proj = (const float*)d_in[10];
  const float* ln_w     = (const float*)d_in[11];
  const float* ln_b     = (const float*)d_in[12];
  const float* dec_w    = (const float*)d_in[13];
  const float* dec_b    = (const float*)d_in[14];
  float* out = (float*)d_out;

  float* ws = (float*)d_ws;
  u16* WtIn  = (u16*)ws;
  u16* WtOut = WtIn + (long)2*NPAD*DMODEL;
  float* gbase = ws + 311296 + 131072;

  int NB = 8;
  while (NB > 1) {
    const long Mb = (long)NB * SEQ;
    const long bytes = (442368L + Mb * 2064L + 4096) * 4;
    if ((size_t)bytes <= ws_size) break;
    NB >>= 1;
  }
  const long Mb = (long)NB * SEQ;

  float* h    = gbase;              // Mb*256
  float* zbuf = h    + Mb*DMODEL;   // Mb*512
  float* xbc  = zbuf + Mb*DIN;      // Mb*640 ; aliased later by Sloc / tmp256
  float* xs   = xbc  + Mb*CONVDIM;  // Mb*512 ; hb(bf16) -> conv x -> y -> gb(bf16)
  float* Bb   = xs   + Mb*DIN;      // Mb*64
  float* Cb   = Bb   + Mb*DSTATE;   // Mb*64
  float* dtb  = Cb   + Mb*DSTATE;   // Mb*8
  float* lab  = dtb  + Mb*NH;       // Mb*8 (log dA)
  float* Pb   = lab  + Mb*NH;       // <= 2048
  float* Sloc   = xbc;              // alias: Mb*256 floats
  float* tmp256 = xbc;              // alias

  cvt_inw <<<dim3(2*NPAD),   dim3(256), 0, stream>>>(in_proj,  WtIn);
  cvt_outw<<<dim3(2*DMODEL), dim3(256), 0, stream>>>(out_proj, WtOut);

  const int ngroups = B_SZ / NB;
  for (int g = 0; g < ngroups; ++g) {
    const float* xg = x + (long)g*NB*SEQ*64;

    enc_kernel<<<dim3((int)(Mb/32)), dim3(256), 0, stream>>>(xg, enc_w, enc_b, h);

    for (int l = 0; l < 2; ++l) {
      cvt_hb<<<dim3((int)(Mb/4)), dim3(256), 0, stream>>>(h, (u16*)xs);
      inproj_mfma<<<dim3((int)(Mb/128), NPAD/64), dim3(256), 0, stream>>>(
          (u16*)xs, WtIn + (long)l*NPAD*DMODEL, zbuf, xbc, dtb, lab,
          dt_bias + l*NH, A_log + l*NH);
      conv_kernel<<<dim3((int)(Mb*CONVDIM/256)), dim3(256), 0, stream>>>(
          xbc, conv_w + (long)l*CONVDIM*4, conv_b + (long)l*CONVDIM, xs, Bb, Cb);
      scanS_kernel<<<dim3(NB*8*NCHUNK), dim3(256), 0, stream>>>(xs, Bb, lab, dtb, Sloc, Pb);
      scanMid_kernel<<<dim3(NB*8, 64), dim3(64), 0, stream>>>(Sloc, Pb);
      scanY_kernel<<<dim3(NB*8*NCHUNK), dim3(512), 0, stream>>>(xs, Bb, Cb, lab, dtb, Sloc, Dp + l*NH);
      gnorm_kernel<<<dim3((int)Mb), dim3(256), 0, stream>>>(xs, zbuf, norm_w + (long)l*DIN);
      outproj_mfma<<<dim3((int)(Mb/128), 4), dim3(256), 0, stream>>>(
          (u16*)xs, WtOut + (long)l*DMODEL*DIN, h, tmp256);
      ln_kernel<<<dim3((int)(Mb/4)), dim3(256), 0, stream>>>(tmp256, h, ln_w + l*DMODEL, ln_b + l*DMODEL);
    }

    dec_kernel<<<dim3(NB*10), dim3(64), 0, stream>>>(h, dec_w, dec_b, out + (long)g*NB*10);
  }
}

// Round 6
// 681.628 us; speedup vs baseline: 6.4699x; 1.2509x over previous
//
#include <hip/hip_runtime.h>
#include <hip/hip_bf16.h>
#include <math.h>

// ---- model constants ----
#define B_SZ    8
#define SEQ     4096
#define DMODEL  256
#define DIN     512     // d_inner
#define DSTATE  64
#define NH      8
#define HD      64
#define CONVDIM 640
#define DPROJ   1160
#define NPAD    1216    // DPROJ padded to 19*64
#define NCHUNK  32      // scan chunks per (b,h)
#define CLEN    128     // SEQ / NCHUNK
#define STR64   68      // LDS row stride (shorts) for K=64 tiles
#define STR128  132     // LDS row stride (shorts) for K=128 tiles

typedef unsigned long long u64;
typedef unsigned int u32;
typedef unsigned short u16;
typedef __attribute__((ext_vector_type(8))) short bf16x8;
typedef __attribute__((ext_vector_type(4))) float f32x4;

__device__ __forceinline__ float siluf(float v){ return v / (1.f + expf(-v)); }
__device__ __forceinline__ u16 f2bf(float f){ __hip_bfloat16 h = __float2bfloat16(f); return *(u16*)&h; }
__device__ __forceinline__ float bf2f(u16 u){ union{u32 i; float f;} t; t.i = ((u32)u)<<16; return t.f; }
__device__ __forceinline__ bf16x8 ldfrag(const u16* base){
  union { u64 u[2]; bf16x8 v; } t;
  const u64* p = (const u64*)base;
  t.u[0] = p[0]; t.u[1] = p[1];
  return t.v;
}

// ---------------- weight conversion (once per launch) ----------------
__global__ __launch_bounds__(256) void cvt_inw(const float* __restrict__ W, u16* __restrict__ Wt)
{
  const int blk = blockIdx.x;
  const int l = blk / NPAD, n = blk % NPAD;
  const int k = threadIdx.x;
  float v = 0.f;
  if (n < DPROJ) v = W[((long)l*DMODEL + k)*DPROJ + n];
  Wt[((long)l*NPAD + n)*DMODEL + k] = f2bf(v);
}

__global__ __launch_bounds__(256) void cvt_outw(const float* __restrict__ W, u16* __restrict__ Wt)
{
  const int blk = blockIdx.x;
  const int l = blk / DMODEL, n = blk % DMODEL;
  #pragma unroll
  for (int q = 0; q < 2; ++q) {
    const int k = threadIdx.x + q*256;
    const float v = W[((long)l*DIN + k)*DMODEL + n];
    Wt[((long)l*DMODEL + n)*DIN + k] = f2bf(v);
  }
}

// ---------------- encoder GEMM; writes h fp32 + hb bf16 ----------------
__global__ __launch_bounds__(256) void enc_kernel(const float* __restrict__ x,
    const float* __restrict__ W, const float* __restrict__ bias,
    float* __restrict__ h, u16* __restrict__ hb)
{
  __shared__ float xl[32*64];
  const int tid = threadIdx.x;
  const long t0 = (long)blockIdx.x * 32;
  for (int i = tid; i < 32*64; i += 256) xl[i] = x[t0*64 + i];
  __syncthreads();
  float acc[32];
  const float bv = bias[tid];
  #pragma unroll
  for (int tok = 0; tok < 32; ++tok) acc[tok] = bv;
  for (int k = 0; k < 64; ++k) {
    const float wv = W[k*DMODEL + tid];
    #pragma unroll
    for (int tok = 0; tok < 32; ++tok) acc[tok] += xl[tok*64 + k] * wv;
  }
  #pragma unroll
  for (int tok = 0; tok < 32; ++tok) {
    h [(t0 + tok)*DMODEL + tid] = acc[tok];
    hb[(t0 + tok)*DMODEL + tid] = f2bf(acc[tok]);
  }
}

// ---------------- in_proj MFMA GEMM; z/xBC out bf16, dt(softplus) + log dA fp32 ----------------
__global__ __launch_bounds__(256) void inproj_mfma(const u16* __restrict__ hb,
    const u16* __restrict__ Wt, u16* __restrict__ zbuf, u16* __restrict__ xbc,
    float* __restrict__ dtb, float* __restrict__ lab,
    const float* __restrict__ dt_bias, const float* __restrict__ A_log)
{
  __shared__ u16 Asl[128*36];
  __shared__ u16 Bsl[64*36];
  const int tid = threadIdx.x;
  const long m0 = (long)blockIdx.x * 128;
  const int n0 = blockIdx.y * 64;
  const int w = tid >> 6, lane = tid & 63;
  const int q = lane >> 4, l16 = lane & 15;
  const int arow = tid & 127, aseg = tid >> 7;
  const int brow = tid >> 2,  bseg = tid & 3;
  f32x4 acc[2][4] = {{{0.f,0.f,0.f,0.f}}};
  for (int k0 = 0; k0 < DMODEL; k0 += 32) {
    {
      const u64* src = (const u64*)(hb + (m0 + arow)*DMODEL + k0 + aseg*16);
      u64* dst = (u64*)(&Asl[arow*36 + aseg*16]);
      u64 x0=src[0], x1=src[1], x2=src[2], x3=src[3];
      dst[0]=x0; dst[1]=x1; dst[2]=x2; dst[3]=x3;
    }
    {
      const u64* src = (const u64*)(Wt + (long)(n0 + brow)*DMODEL + k0 + bseg*8);
      u64* dst = (u64*)(&Bsl[brow*36 + bseg*8]);
      u64 x0=src[0], x1=src[1];
      dst[0]=x0; dst[1]=x1;
    }
    __syncthreads();
    bf16x8 af[2], bfr[4];
    #pragma unroll
    for (int mi=0;mi<2;mi++) af[mi] = ldfrag(&Asl[(w*32 + mi*16 + l16)*36 + q*8]);
    #pragma unroll
    for (int nj=0;nj<4;nj++) bfr[nj] = ldfrag(&Bsl[(nj*16 + l16)*36 + q*8]);
    #pragma unroll
    for (int mi=0;mi<2;mi++)
      #pragma unroll
      for (int nj=0;nj<4;nj++)
        acc[mi][nj] = __builtin_amdgcn_mfma_f32_16x16x32_bf16(af[mi], bfr[nj], acc[mi][nj], 0,0,0);
    __syncthreads();
  }
  #pragma unroll
  for (int mi=0;mi<2;mi++){
    #pragma unroll
    for (int nj=0;nj<4;nj++){
      const int col = n0 + nj*16 + l16;
      #pragma unroll
      for (int r=0;r<4;r++){
        const long row = m0 + w*32 + mi*16 + q*4 + r;
        const float v = acc[mi][nj][r];
        if (col < DIN) zbuf[row*DIN + col] = f2bf(v);
        else if (col < DIN + CONVDIM) xbc[row*CONVDIM + (col - DIN)] = f2bf(v);
        else if (col < DPROJ) {
          const int hh = col - (DIN + CONVDIM);
          const float dv = v + dt_bias[hh];
          const float sp = dv > 20.f ? dv : log1pf(expf(dv));
          dtb[row*NH + hh] = sp;
          lab[row*NH + hh] = sp * (-expf(A_log[hh]));   // log dA
        }
      }
    }
  }
}

// ---------------- out_proj MFMA GEMM + residual ----------------
__global__ __launch_bounds__(256) void outproj_mfma(const u16* __restrict__ gb,
    const u16* __restrict__ Wt, const float* __restrict__ resid, float* __restrict__ outb)
{
  __shared__ u16 Asl[128*36];
  __shared__ u16 Bsl[64*36];
  const int tid = threadIdx.x;
  const long m0 = (long)blockIdx.x * 128;
  const int n0 = blockIdx.y * 64;
  const int w = tid >> 6, lane = tid & 63;
  const int q = lane >> 4, l16 = lane & 15;
  const int arow = tid & 127, aseg = tid >> 7;
  const int brow = tid >> 2,  bseg = tid & 3;
  f32x4 acc[2][4] = {{{0.f,0.f,0.f,0.f}}};
  for (int k0 = 0; k0 < DIN; k0 += 32) {
    {
      const u64* src = (const u64*)(gb + (m0 + arow)*1024 + k0 + aseg*16);
      u64* dst = (u64*)(&Asl[arow*36 + aseg*16]);
      u64 x0=src[0], x1=src[1], x2=src[2], x3=src[3];
      dst[0]=x0; dst[1]=x1; dst[2]=x2; dst[3]=x3;
    }
    {
      const u64* src = (const u64*)(Wt + (long)(n0 + brow)*DIN + k0 + bseg*8);
      u64* dst = (u64*)(&Bsl[brow*36 + bseg*8]);
      u64 x0=src[0], x1=src[1];
      dst[0]=x0; dst[1]=x1;
    }
    __syncthreads();
    bf16x8 af[2], bfr[4];
    #pragma unroll
    for (int mi=0;mi<2;mi++) af[mi] = ldfrag(&Asl[(w*32 + mi*16 + l16)*36 + q*8]);
    #pragma unroll
    for (int nj=0;nj<4;nj++) bfr[nj] = ldfrag(&Bsl[(nj*16 + l16)*36 + q*8]);
    #pragma unroll
    for (int mi=0;mi<2;mi++)
      #pragma unroll
      for (int nj=0;nj<4;nj++)
        acc[mi][nj] = __builtin_amdgcn_mfma_f32_16x16x32_bf16(af[mi], bfr[nj], acc[mi][nj], 0,0,0);
    __syncthreads();
  }
  #pragma unroll
  for (int mi=0;mi<2;mi++){
    #pragma unroll
    for (int nj=0;nj<4;nj++){
      const int col = n0 + nj*16 + l16;
      #pragma unroll
      for (int r=0;r<4;r++){
        const long row = m0 + w*32 + mi*16 + q*4 + r;
        outb[row*DMODEL + col] = acc[mi][nj][r] + resid[row*DMODEL + col];
      }
    }
  }
}

// ---------------- depthwise causal conv + SiLU, bf16 in/out, 4 ch/thread ----------------
__global__ __launch_bounds__(256) void conv_kernel(const u16* __restrict__ xbc,
    const float* __restrict__ cw, const float* __restrict__ cb,
    u16* __restrict__ xsx, u16* __restrict__ Bb, u16* __restrict__ Cb)
{
  const long idx = (long)blockIdx.x * 256 + threadIdx.x;   // Mb*160 threads
  const int c4 = (int)(idx % 160) * 4;
  const long bt = idx / 160;
  const int t = (int)(bt & (SEQ-1));
  const float4 b4 = *(const float4*)(cb + c4);
  float a0=b4.x, a1=b4.y, a2=b4.z, a3=b4.w;
  const float4 w0 = *(const float4*)(cw + (c4+0)*4);  // taps for channel c4+0
  const float4 w1 = *(const float4*)(cw + (c4+1)*4);
  const float4 w2 = *(const float4*)(cw + (c4+2)*4);
  const float4 w3 = *(const float4*)(cw + (c4+3)*4);
  const float* W0=(const float*)&w0; const float* W1=(const float*)&w1;
  const float* W2=(const float*)&w2; const float* W3=(const float*)&w3;
  #pragma unroll
  for (int k = 0; k < 4; ++k) {
    const int tt = t - 3 + k;
    if (tt >= 0) {
      const u64 v = *(const u64*)(xbc + (bt-3+k)*CONVDIM + c4);
      a0 += bf2f((u16)(v      )) * W0[k];
      a1 += bf2f((u16)(v >> 16)) * W1[k];
      a2 += bf2f((u16)(v >> 32)) * W2[k];
      a3 += bf2f((u16)(v >> 48)) * W3[k];
    }
  }
  a0 = siluf(a0); a1 = siluf(a1); a2 = siluf(a2); a3 = siluf(a3);
  const u64 r = (u64)f2bf(a0) | ((u64)f2bf(a1)<<16) | ((u64)f2bf(a2)<<32) | ((u64)f2bf(a3)<<48);
  if (c4 < DIN)            *(u64*)(xsx + bt*DIN + c4) = r;
  else if (c4 < DIN+DSTATE)*(u64*)(Bb  + bt*DSTATE + (c4-DIN)) = r;
  else                     *(u64*)(Cb  + bt*DSTATE + (c4-DIN-DSTATE)) = r;
}

// ---------------- SSD phase A: per chunk-head local state via MFMA ----------------
__global__ __launch_bounds__(256) void scanS_kernel(const u16* __restrict__ xsx,
    const u16* __restrict__ Bb, const float* __restrict__ lab, const float* __restrict__ dtb,
    float* __restrict__ Sloc, float* __restrict__ Pb)
{
  __shared__ __align__(16) u16 Btr[64*STR128];   // [n][s]
  __shared__ __align__(16) u16 Uw[64*STR128];    // [p][s]
  __shared__ float cexpL[128];
  const int wg = blockIdx.x;
  const int c = wg & (NCHUNK-1), bh = wg >> 5, hh = bh & (NH-1), b = bh >> 3;
  const int tid = threadIdx.x;
  const long bt0 = (long)b*SEQ + c*CLEN;
  if (tid < 64) {   // wave 0: inclusive prefix of log dA over 128 steps
    float a0 = lab[(bt0+tid)*NH + hh];
    float a1 = lab[(bt0+64+tid)*NH + hh];
    const float d0 = dtb[(bt0+tid)*NH + hh];
    const float d1 = dtb[(bt0+64+tid)*NH + hh];
    #pragma unroll
    for (int o=1;o<64;o<<=1){
      const float t0=__shfl_up(a0,o), t1=__shfl_up(a1,o);
      if (tid>=o){a0+=t0;a1+=t1;}
    }
    a1 += __shfl(a0,63);
    const float ctot = __shfl(a1,63);
    cexpL[tid]    = d0*__expf(ctot - a0);
    cexpL[tid+64] = d1*__expf(ctot - a1);
    if (tid==0) Pb[wg] = __expf(ctot);
  }
  __syncthreads();
  {
    const int v = tid & 63, r0 = tid >> 6;
    #pragma unroll 4
    for (int k=0;k<32;k++){
      const int s = r0 + k*4;
      Btr[v*STR128 + s] = Bb[(bt0+s)*DSTATE + v];
      Uw[v*STR128 + s]  = f2bf(cexpL[s]*bf2f(xsx[(bt0+s)*DIN + hh*HD + v]));
    }
  }
  __syncthreads();
  const int w = tid>>6, lane = tid&63, q = lane>>4, l16 = lane&15;
  f32x4 acc[4] = {};
  #pragma unroll
  for (int ks=0;ks<4;ks++){
    const bf16x8 af = ldfrag(&Uw[(w*16+l16)*STR128 + ks*32 + q*8]);
    #pragma unroll
    for (int nj=0;nj<4;nj++){
      const bf16x8 bf = ldfrag(&Btr[(nj*16+l16)*STR128 + ks*32 + q*8]);
      acc[nj] = __builtin_amdgcn_mfma_f32_16x16x32_bf16(af, bf, acc[nj], 0,0,0);
    }
  }
  const long sb = (long)wg*4096;   // [wg][p][n]
  #pragma unroll
  for (int nj=0;nj<4;nj++)
    #pragma unroll
    for (int r=0;r<4;r++)
      Sloc[sb + (w*16+q*4+r)*64 + nj*16 + l16] = acc[nj][r];
}

// Parallel combine: Sloc[c] := running; run = P[c]*run + tmp
__global__ __launch_bounds__(64) void scanMid_kernel(float* __restrict__ Sloc, const float* __restrict__ Pb)
{
  const int bh = blockIdx.x;
  const int rr = blockIdx.y;
  const int p  = threadIdx.x;
  float run = 0.f;
  for (int c = 0; c < NCHUNK; ++c) {
    const long base = ((long)(bh*NCHUNK + c))*4096 + rr*64 + p;
    const float Pc = Pb[bh*NCHUNK + c];
    const float tmp = Sloc[base];
    Sloc[base] = run;
    run = run*Pc + tmp;
  }
}

// ---------------- SSD phase C: Y = ((C Bt) o L) U + diag(exp(cum)) (C h0) + D*x ----------------
__global__ __launch_bounds__(512) void scanY_kernel(const u16* __restrict__ xsx,
    float* __restrict__ yb, const u16* __restrict__ Bb, const u16* __restrict__ Cb,
    const float* __restrict__ lab, const float* __restrict__ dtb,
    const float* __restrict__ Sinit, const float* __restrict__ Dp)
{
  __shared__ __align__(16) u16 pool[2*128*STR64];  // Bs | Cs; overlaid by Ms[t][s]
  __shared__ __align__(16) u16 Ut[64*STR128];      // [p][s]
  __shared__ __align__(16) u16 h0t[64*STR64];      // [p][n]
  __shared__ float cumL[128];
  __shared__ float dtL[128];
  u16* Bs = pool;
  u16* Cs = pool + 128*STR64;
  u16* Ms = pool;

  const int wg = blockIdx.x;
  const int c = wg & (NCHUNK-1), bh = wg >> 5, hh = bh & (NH-1), b = bh >> 3;
  const int tid = threadIdx.x;
  const long bt0 = (long)b*SEQ + c*CLEN;

  if (tid < 64) {
    float a0 = lab[(bt0+tid)*NH + hh];
    float a1 = lab[(bt0+64+tid)*NH + hh];
    dtL[tid]    = dtb[(bt0+tid)*NH + hh];
    dtL[tid+64] = dtb[(bt0+64+tid)*NH + hh];
    #pragma unroll
    for (int o=1;o<64;o<<=1){
      const float t0=__shfl_up(a0,o), t1=__shfl_up(a1,o);
      if (tid>=o){a0+=t0;a1+=t1;}
    }
    a1 += __shfl(a0,63);
    cumL[tid]=a0; cumL[tid+64]=a1;
  }
  __syncthreads();
  {
    const int n = tid & 63, r0 = tid >> 6;   // 512 threads: r0 in 0..7
    #pragma unroll 4
    for (int k=0;k<16;k++){
      const int s = r0 + k*8;
      Bs[s*STR64 + n] = Bb[(bt0+s)*DSTATE + n];
      Cs[s*STR64 + n] = Cb[(bt0+s)*DSTATE + n];
      Ut[n*STR128 + s] = f2bf(dtL[s]*bf2f(xsx[(bt0+s)*DIN + hh*HD + n]));
    }
    const int n0 = r0*8;
    const float* hp = Sinit + (long)wg*4096 + n*64 + n0;
    #pragma unroll
    for (int j=0;j<8;j++) h0t[n*STR64 + n0 + j] = f2bf(hp[j]);
  }
  __syncthreads();

  const int w = tid>>6, lane = tid&63, q = lane>>4, l16 = lane&15;
  f32x4 accG[8] = {};
  f32x4 accI[4] = {};
  #pragma unroll
  for (int ks=0;ks<2;ks++){
    const bf16x8 af = ldfrag(&Cs[(w*16+l16)*STR64 + ks*32 + q*8]);
    #pragma unroll
    for (int nj=0;nj<8;nj++)
      accG[nj] = __builtin_amdgcn_mfma_f32_16x16x32_bf16(af, ldfrag(&Bs[(nj*16+l16)*STR64 + ks*32 + q*8]), accG[nj], 0,0,0);
    #pragma unroll
    for (int nj=0;nj<4;nj++)
      accI[nj] = __builtin_amdgcn_mfma_f32_16x16x32_bf16(af, ldfrag(&h0t[(nj*16+l16)*STR64 + ks*32 + q*8]), accI[nj], 0,0,0);
  }
  __syncthreads();
  #pragma unroll
  for (int nj=0;nj<8;nj++){
    const int s = nj*16 + l16;
    #pragma unroll
    for (int r=0;r<4;r++){
      const int t = w*16 + q*4 + r;
      const float v = (s<=t) ? accG[nj][r]*__expf(cumL[t]-cumL[s]) : 0.f;
      Ms[t*STR128 + s] = f2bf(v);
    }
  }
  __syncthreads();
  f32x4 accY[4] = {};
  #pragma unroll
  for (int ks=0;ks<4;ks++){
    const bf16x8 af = ldfrag(&Ms[(w*16+l16)*STR128 + ks*32 + q*8]);
    #pragma unroll
    for (int nj=0;nj<4;nj++)
      accY[nj] = __builtin_amdgcn_mfma_f32_16x16x32_bf16(af, ldfrag(&Ut[(nj*16+l16)*STR128 + ks*32 + q*8]), accY[nj], 0,0,0);
  }
  const float Dv = Dp[hh];
  #pragma unroll
  for (int nj=0;nj<4;nj++){
    const int p = nj*16 + l16;
    #pragma unroll
    for (int r=0;r<4;r++){
      const int t = w*16 + q*4 + r;
      const long a = (bt0+t)*DIN + hh*HD + p;
      const float xv = bf2f(xsx[a]);
      yb[a] = accY[nj][r] + __expf(cumL[t])*accI[nj][r] + Dv*xv;
    }
  }
}

// ---------------- y*silu(z) + RMSNorm; emits bf16 A-operand in place over yb ----------------
__global__ __launch_bounds__(256) void gnorm_kernel(float* __restrict__ y_io,
    const u16* __restrict__ zb, const float* __restrict__ nw)
{
  const long row = blockIdx.x;
  const int tid = threadIdx.x;
  float g[2];
  #pragma unroll
  for (int q=0;q<2;q++){
    const int cc = tid + q*256;
    const float yv = y_io[row*DIN + cc];
    const float zv = bf2f(zb[row*DIN + cc]);
    g[q] = yv * siluf(zv);
  }
  float ss = g[0]*g[0] + g[1]*g[1];
  #pragma unroll
  for (int o=32;o;o>>=1) ss += __shfl_down(ss, o);
  __shared__ float red[4];
  if ((tid & 63) == 0) red[tid>>6] = ss;
  __syncthreads();
  const float tot = red[0]+red[1]+red[2]+red[3];
  const float scale = rsqrtf(tot * (1.f/512.f) + 1e-5f);
  u16* gp = (u16*)(y_io + row*DIN);
  #pragma unroll
  for (int q=0;q<2;q++){
    const int cc = tid + q*256;
    gp[cc] = f2bf(g[q] * scale * nw[cc]);
  }
}

// ---------------- LayerNorm; writes h fp32 + hb bf16 ----------------
__global__ __launch_bounds__(256) void ln_kernel(const float* __restrict__ in,
    float* __restrict__ h, u16* __restrict__ hb,
    const float* __restrict__ w, const float* __restrict__ bb)
{
  const int lane = threadIdx.x & 63;
  const int wid  = threadIdx.x >> 6;
  const long row = (long)blockIdx.x * 4 + wid;
  const float* r = in + row*DMODEL;
  float v[4]; float sum = 0.f, sq = 0.f;
  #pragma unroll
  for (int q=0;q<4;q++){ v[q] = r[lane + q*64]; sum += v[q]; sq += v[q]*v[q]; }
  #pragma unroll
  for (int o=32;o;o>>=1){ sum += __shfl_xor(sum,o); sq += __shfl_xor(sq,o); }
  const float mu = sum * (1.f/256.f);
  const float var = sq * (1.f/256.f) - mu*mu;
  const float rs = rsqrtf(var + 1e-5f);
  #pragma unroll
  for (int q=0;q<4;q++){
    const int cc = lane + q*64;
    const float o = (v[q]-mu)*rs*w[cc] + bb[cc];
    h [row*DMODEL + cc] = o;
    hb[row*DMODEL + cc] = f2bf(o);
  }
}

// ---------------- decoder (fp32 output) ----------------
__global__ __launch_bounds__(64) void dec_kernel(const float* __restrict__ h,
    const float* __restrict__ W, const float* __restrict__ bias, float* __restrict__ out)
{
  const int wg = blockIdx.x;
  const int b = wg / 10, o = wg % 10;
  const int lane = threadIdx.x;
  const float* r = h + ((long)b*SEQ + SEQ-1)*DMODEL;
  float s = 0.f;
  #pragma unroll
  for (int q=0;q<4;q++){ const int k = lane + q*64; s += r[k]*W[k*10+o]; }
  #pragma unroll
  for (int o2=32;o2;o2>>=1) s += __shfl_down(s, o2);
  if (lane == 0) out[wg] = s + bias[o];
}

extern "C" void kernel_launch(void* const* d_in, const int* in_sizes, int n_in,
                              void* d_out, int out_size, void* d_ws, size_t ws_size,
                              hipStream_t stream) {
  const float* x        = (const float*)d_in[0];
  const float* enc_w    = (const float*)d_in[1];
  const float* enc_b    = (const float*)d_in[2];
  const float* in_proj  = (const float*)d_in[3];
  const float* conv_w   = (const float*)d_in[4];
  const float* conv_b   = (const float*)d_in[5];
  const float* dt_bias  = (const float*)d_in[6];
  const float* A_log    = (const float*)d_in[7];
  const float* Dp       = (const float*)d_in[8];
  const float* norm_w   = (const float*)d_in[9];
  const float* out_proj = (const float*)d_in[10];
  const float* ln_w     = (const float*)d_in[11];
  const float* ln_b     = (const float*)d_in[12];
  const float* dec_w    = (const float*)d_in[13];
  const float* dec_b    = (const float*)d_in[14];
  float* out = (float*)d_out;

  float* ws = (float*)d_ws;
  u16* WtIn  = (u16*)ws;                       // 2*NPAD*256 shorts
  u16* WtOut = WtIn + (long)2*NPAD*DMODEL;     // 2*256*512 shorts
  float* gbase = ws + 311296 + 131072;         // = ws + 442368 floats

  // Per-token fp32-equivalents: h 256 + hb 128 + z 256 + xbc 320 + xsx 256 + yb 512
  //                             + Bb 32 + Cb 32 + dtb 8 + lab 8 = 1808
  int NB = 8;
  while (NB > 1) {
    const long Mb = (long)NB * SEQ;
    const long bytes = (442368L + Mb * 1808L + 4096) * 4;
    if ((size_t)bytes <= ws_size) break;
    NB >>= 1;
  }
  const long Mb = (long)NB * SEQ;

  float* h    = gbase;                    // Mb*256 f
  u16*   hb   = (u16*)(h + Mb*DMODEL);    // Mb*256 u16
  u16*   zbuf = hb + Mb*DMODEL;           // Mb*512 u16
  u16*   xbc  = zbuf + Mb*DIN;            // Mb*640 u16 ; aliased by Sloc/tmp256 (Mb*256 f fits in Mb*320 f)
  u16*   xsx  = xbc + Mb*CONVDIM;         // Mb*512 u16
  float* yb   = (float*)(xsx + Mb*DIN);   // Mb*512 f ; gb bf16 written in place (stride 1024 shorts)
  u16*   Bb   = (u16*)(yb + Mb*DIN);      // Mb*64 u16
  u16*   Cb   = Bb + Mb*DSTATE;           // Mb*64 u16
  float* dtb  = (float*)(Cb + Mb*DSTATE); // Mb*8 f
  float* lab  = dtb + Mb*NH;              // Mb*8 f (log dA)
  float* Pb   = lab + Mb*NH;              // <= 2048
  float* Sloc   = (float*)xbc;            // alias: xbc dead after conv
  float* tmp256 = (float*)xbc;            // alias: Sloc dead after scanY

  cvt_inw <<<dim3(2*NPAD),   dim3(256), 0, stream>>>(in_proj,  WtIn);
  cvt_outw<<<dim3(2*DMODEL), dim3(256), 0, stream>>>(out_proj, WtOut);

  const int ngroups = B_SZ / NB;
  for (int g = 0; g < ngroups; ++g) {
    const float* xg = x + (long)g*NB*SEQ*64;

    enc_kernel<<<dim3((int)(Mb/32)), dim3(256), 0, stream>>>(xg, enc_w, enc_b, h, hb);

    for (int l = 0; l < 2; ++l) {
      inproj_mfma<<<dim3((int)(Mb/128), NPAD/64), dim3(256), 0, stream>>>(
          hb, WtIn + (long)l*NPAD*DMODEL, zbuf, xbc, dtb, lab,
          dt_bias + l*NH, A_log + l*NH);
      conv_kernel<<<dim3((int)(Mb*160/256)), dim3(256), 0, stream>>>(
          xbc, conv_w + (long)l*CONVDIM*4, conv_b + (long)l*CONVDIM, xsx, Bb, Cb);
      scanS_kernel<<<dim3(NB*8*NCHUNK), dim3(256), 0, stream>>>(xsx, Bb, lab, dtb, Sloc, Pb);
      scanMid_kernel<<<dim3(NB*8, 64), dim3(64), 0, stream>>>(Sloc, Pb);
      scanY_kernel<<<dim3(NB*8*NCHUNK), dim3(512), 0, stream>>>(xsx, yb, Bb, Cb, lab, dtb, Sloc, Dp + l*NH);
      gnorm_kernel<<<dim3((int)Mb), dim3(256), 0, stream>>>(yb, zbuf, norm_w + (long)l*DIN);
      outproj_mfma<<<dim3((int)(Mb/128), 4), dim3(256), 0, stream>>>(
          (u16*)yb, WtOut + (long)l*DMODEL*DIN, h, tmp256);
      ln_kernel<<<dim3((int)(Mb/4)), dim3(256), 0, stream>>>(tmp256, h, hb, ln_w + l*DMODEL, ln_b + l*DMODEL);
    }

    dec_kernel<<<dim3(NB*10), dim3(64), 0, stream>>>(h, dec_w, dec_b, out + (long)g*NB*10);
  }
}

// Round 8
// 612.897 us; speedup vs baseline: 7.1954x; 1.1121x over previous
//
#include <hip/hip_runtime.h>
#include <hip/hip_bf16.h>
#include <math.h>

// ---- model constants ----
#define B_SZ    8
#define SEQ     4096
#define DMODEL  256
#define DIN     512     // d_inner
#define DSTATE  64
#define NH      8
#define HD      64
#define CONVDIM 640
#define DPROJ   1160
#define NPAD    1280    // DPROJ padded to 10*128
#define NCHUNK  32      // scan chunks per (b,h)
#define CLEN    128     // SEQ / NCHUNK
#define STR64   68      // LDS row stride (shorts) for K=64 tiles
#define STR128  132     // LDS row stride (shorts) for K=128 tiles

typedef unsigned long long u64;
typedef unsigned int u32;
typedef unsigned short u16;
typedef __attribute__((ext_vector_type(8))) short bf16x8;
typedef __attribute__((ext_vector_type(4))) float f32x4;

__device__ __forceinline__ float siluf(float v){ return v / (1.f + expf(-v)); }
__device__ __forceinline__ u16 f2bf(float f){ __hip_bfloat16 h = __float2bfloat16(f); return *(u16*)&h; }
__device__ __forceinline__ float bf2f(u16 u){ union{u32 i; float f;} t; t.i = ((u32)u)<<16; return t.f; }
__device__ __forceinline__ bf16x8 ldfrag(const u16* base){
  union { u64 u[2]; bf16x8 v; } t;
  const u64* p = (const u64*)base;
  t.u[0] = p[0]; t.u[1] = p[1];
  return t.v;
}

// ---------------- weight conversion (once per launch) ----------------
__global__ __launch_bounds__(256) void cvt_inw(const float* __restrict__ W, u16* __restrict__ Wt)
{
  const int blk = blockIdx.x;
  const int l = blk / NPAD, n = blk % NPAD;
  const int k = threadIdx.x;
  float v = 0.f;
  if (n < DPROJ) v = W[((long)l*DMODEL + k)*DPROJ + n];
  Wt[((long)l*NPAD + n)*DMODEL + k] = f2bf(v);
}

__global__ __launch_bounds__(256) void cvt_outw(const float* __restrict__ W, u16* __restrict__ Wt)
{
  const int blk = blockIdx.x;
  const int l = blk / DMODEL, n = blk % DMODEL;
  #pragma unroll
  for (int q = 0; q < 2; ++q) {
    const int k = threadIdx.x + q*256;
    const float v = W[((long)l*DIN + k)*DMODEL + n];
    Wt[((long)l*DMODEL + n)*DIN + k] = f2bf(v);
  }
}

// ---------------- encoder GEMM; writes h fp32 + hb bf16 ----------------
__global__ __launch_bounds__(256) void enc_kernel(const float* __restrict__ x,
    const float* __restrict__ W, const float* __restrict__ bias,
    float* __restrict__ h, u16* __restrict__ hb)
{
  __shared__ float xl[32*64];
  const int tid = threadIdx.x;
  const long t0 = (long)blockIdx.x * 32;
  for (int i = tid; i < 32*64; i += 256) xl[i] = x[t0*64 + i];
  __syncthreads();
  float acc[32];
  const float bv = bias[tid];
  #pragma unroll
  for (int tok = 0; tok < 32; ++tok) acc[tok] = bv;
  for (int k = 0; k < 64; ++k) {
    const float wv = W[k*DMODEL + tid];
    #pragma unroll
    for (int tok = 0; tok < 32; ++tok) acc[tok] += xl[tok*64 + k] * wv;
  }
  #pragma unroll
  for (int tok = 0; tok < 32; ++tok) {
    h [(t0 + tok)*DMODEL + tid] = acc[tok];
    hb[(t0 + tok)*DMODEL + tid] = f2bf(acc[tok]);
  }
}

// ---------------- in_proj MFMA GEMM 128x128 tile, BK=32 ----------------
__global__ __launch_bounds__(256) void inproj_mfma(const u16* __restrict__ hb,
    const u16* __restrict__ Wt, u16* __restrict__ zbuf, u16* __restrict__ xbc,
    float* __restrict__ dtb, float* __restrict__ lab,
    const float* __restrict__ dt_bias, const float* __restrict__ A_log)
{
  __shared__ u16 Asl[128*36];
  __shared__ u16 Bsl[128*36];
  const int tid = threadIdx.x;
  const long m0 = (long)blockIdx.x * 128;
  const int n0 = blockIdx.y * 128;
  const int w = tid >> 6, lane = tid & 63;
  const int q = lane >> 4, l16 = lane & 15;
  const int srow = tid >> 1, sseg = tid & 1;   // 2 lanes/row, 16 shorts (32 B) each
  f32x4 acc[2][8] = {{{0.f,0.f,0.f,0.f}}};
  for (int k0 = 0; k0 < DMODEL; k0 += 32) {
    {
      const u64* s = (const u64*)(hb + (m0 + srow)*DMODEL + k0 + sseg*16);
      u64 a=s[0], b=s[1], c=s[2], d=s[3];
      u64* dst = (u64*)(&Asl[srow*36 + sseg*16]);
      dst[0]=a; dst[1]=b; dst[2]=c; dst[3]=d;
    }
    {
      const u64* s = (const u64*)(Wt + (long)(n0 + srow)*DMODEL + k0 + sseg*16);
      u64 a=s[0], b=s[1], c=s[2], d=s[3];
      u64* dst = (u64*)(&Bsl[srow*36 + sseg*16]);
      dst[0]=a; dst[1]=b; dst[2]=c; dst[3]=d;
    }
    __syncthreads();
    bf16x8 af[2], bfr[8];
    #pragma unroll
    for (int mi=0;mi<2;mi++) af[mi] = ldfrag(&Asl[(w*32 + mi*16 + l16)*36 + q*8]);
    #pragma unroll
    for (int nj=0;nj<8;nj++) bfr[nj] = ldfrag(&Bsl[(nj*16 + l16)*36 + q*8]);
    #pragma unroll
    for (int mi=0;mi<2;mi++)
      #pragma unroll
      for (int nj=0;nj<8;nj++)
        acc[mi][nj] = __builtin_amdgcn_mfma_f32_16x16x32_bf16(af[mi], bfr[nj], acc[mi][nj], 0,0,0);
    __syncthreads();
  }
  #pragma unroll
  for (int mi=0;mi<2;mi++){
    #pragma unroll
    for (int nj=0;nj<8;nj++){
      const int col = n0 + nj*16 + l16;
      #pragma unroll
      for (int r=0;r<4;r++){
        const long row = m0 + w*32 + mi*16 + q*4 + r;
        const float v = acc[mi][nj][r];
        if (col < DIN) zbuf[row*DIN + col] = f2bf(v);
        else if (col < DIN + CONVDIM) xbc[row*CONVDIM + (col - DIN)] = f2bf(v);
        else if (col < DPROJ) {
          const int hh = col - (DIN + CONVDIM);
          const float dv = v + dt_bias[hh];
          const float sp = dv > 20.f ? dv : log1pf(expf(dv));
          dtb[row*NH + hh] = sp;
          lab[row*NH + hh] = sp * (-expf(A_log[hh]));   // log dA
        }
      }
    }
  }
}

// ---------------- out_proj MFMA GEMM 128x128 tile + residual ----------------
__global__ __launch_bounds__(256) void outproj_mfma(const u16* __restrict__ gb,
    const u16* __restrict__ Wt, const float* __restrict__ resid, float* __restrict__ outb)
{
  __shared__ u16 Asl[128*36];
  __shared__ u16 Bsl[128*36];
  const int tid = threadIdx.x;
  const long m0 = (long)blockIdx.x * 128;
  const int n0 = blockIdx.y * 128;
  const int w = tid >> 6, lane = tid & 63;
  const int q = lane >> 4, l16 = lane & 15;
  const int srow = tid >> 1, sseg = tid & 1;
  f32x4 acc[2][8] = {{{0.f,0.f,0.f,0.f}}};
  for (int k0 = 0; k0 < DIN; k0 += 32) {
    {
      const u64* s = (const u64*)(gb + (m0 + srow)*DIN + k0 + sseg*16);
      u64 a=s[0], b=s[1], c=s[2], d=s[3];
      u64* dst = (u64*)(&Asl[srow*36 + sseg*16]);
      dst[0]=a; dst[1]=b; dst[2]=c; dst[3]=d;
    }
    {
      const u64* s = (const u64*)(Wt + (long)(n0 + srow)*DIN + k0 + sseg*16);
      u64 a=s[0], b=s[1], c=s[2], d=s[3];
      u64* dst = (u64*)(&Bsl[srow*36 + sseg*16]);
      dst[0]=a; dst[1]=b; dst[2]=c; dst[3]=d;
    }
    __syncthreads();
    bf16x8 af[2], bfr[8];
    #pragma unroll
    for (int mi=0;mi<2;mi++) af[mi] = ldfrag(&Asl[(w*32 + mi*16 + l16)*36 + q*8]);
    #pragma unroll
    for (int nj=0;nj<8;nj++) bfr[nj] = ldfrag(&Bsl[(nj*16 + l16)*36 + q*8]);
    #pragma unroll
    for (int mi=0;mi<2;mi++)
      #pragma unroll
      for (int nj=0;nj<8;nj++)
        acc[mi][nj] = __builtin_amdgcn_mfma_f32_16x16x32_bf16(af[mi], bfr[nj], acc[mi][nj], 0,0,0);
    __syncthreads();
  }
  #pragma unroll
  for (int mi=0;mi<2;mi++){
    #pragma unroll
    for (int nj=0;nj<8;nj++){
      const int col = n0 + nj*16 + l16;
      #pragma unroll
      for (int r=0;r<4;r++){
        const long row = m0 + w*32 + mi*16 + q*4 + r;
        outb[row*DMODEL + col] = acc[mi][nj][r] + resid[row*DMODEL + col];
      }
    }
  }
}

// ---------------- depthwise causal conv + SiLU: strip kernel ----------------
// Thread = 8 consecutive timesteps x 4 channels. Weights amortized 8x; 11 loads / 32 outputs.
__global__ __launch_bounds__(256) void conv_kernel(const u16* __restrict__ xbc,
    const float* __restrict__ cw, const float* __restrict__ cb,
    u16* __restrict__ xsx, u16* __restrict__ Bb, u16* __restrict__ Cb)
{
  const long idx = (long)blockIdx.x * 256 + threadIdx.x;   // Mb*20 threads
  const int c4 = (int)(idx % 160) * 4;
  const long bt0 = (idx / 160) * 8;          // strip start (strips never cross batch)
  const int tseq = (int)(bt0 & (SEQ-1));
  const float4 b4 = *(const float4*)(cb + c4);
  const float4 w0v = *(const float4*)(cw + (c4+0)*4);
  const float4 w1v = *(const float4*)(cw + (c4+1)*4);
  const float4 w2v = *(const float4*)(cw + (c4+2)*4);
  const float4 w3v = *(const float4*)(cw + (c4+3)*4);
  const float W0[4] = {w0v.x,w0v.y,w0v.z,w0v.w};
  const float W1[4] = {w1v.x,w1v.y,w1v.z,w1v.w};
  const float W2[4] = {w2v.x,w2v.y,w2v.z,w2v.w};
  const float W3[4] = {w3v.x,w3v.y,w3v.z,w3v.w};
  float i0[11], i1[11], i2[11], i3[11];
  #pragma unroll
  for (int k = 0; k < 11; ++k) {
    u64 v = 0;
    if (tseq - 3 + k >= 0) v = *(const u64*)(xbc + (bt0 - 3 + k)*CONVDIM + c4);
    i0[k]=bf2f((u16)v); i1[k]=bf2f((u16)(v>>16)); i2[k]=bf2f((u16)(v>>32)); i3[k]=bf2f((u16)(v>>48));
  }
  u16* dst; long base; int stride;
  if (c4 < DIN)              { dst = xsx; base = bt0*DIN + c4;              stride = DIN; }
  else if (c4 < DIN+DSTATE)  { dst = Bb;  base = bt0*DSTATE + (c4-DIN);     stride = DSTATE; }
  else                       { dst = Cb;  base = bt0*DSTATE + (c4-DIN-DSTATE); stride = DSTATE; }
  #pragma unroll
  for (int j = 0; j < 8; ++j) {
    float a0=b4.x, a1=b4.y, a2=b4.z, a3=b4.w;
    #pragma unroll
    for (int k = 0; k < 4; ++k) {
      a0 += W0[k]*i0[j+k]; a1 += W1[k]*i1[j+k];
      a2 += W2[k]*i2[j+k]; a3 += W3[k]*i3[j+k];
    }
    a0=siluf(a0); a1=siluf(a1); a2=siluf(a2); a3=siluf(a3);
    const u64 r = (u64)f2bf(a0) | ((u64)f2bf(a1)<<16) | ((u64)f2bf(a2)<<32) | ((u64)f2bf(a3)<<48);
    *(u64*)(dst + base + (long)j*stride) = r;
  }
}

// ---------------- SSD phase A: per chunk-head local state via MFMA ----------------
__global__ __launch_bounds__(256) void scanS_kernel(const u16* __restrict__ xsx,
    const u16* __restrict__ Bb, const float* __restrict__ lab, const float* __restrict__ dtb,
    float* __restrict__ Sloc, float* __restrict__ Pb)
{
  __shared__ __align__(16) u16 Btr[64*STR128];   // [n][s]
  __shared__ __align__(16) u16 Uw[64*STR128];    // [p][s]
  __shared__ float cexpL[128];
  const int wg = blockIdx.x;
  const int c = wg & (NCHUNK-1), bh = wg >> 5, hh = bh & (NH-1), b = bh >> 3;
  const int tid = threadIdx.x;
  const long bt0 = (long)b*SEQ + c*CLEN;
  if (tid < 64) {   // wave 0: inclusive prefix of log dA over 128 steps
    float a0 = lab[(bt0+tid)*NH + hh];
    float a1 = lab[(bt0+64+tid)*NH + hh];
    const float d0 = dtb[(bt0+tid)*NH + hh];
    const float d1 = dtb[(bt0+64+tid)*NH + hh];
    #pragma unroll
    for (int o=1;o<64;o<<=1){
      const float t0=__shfl_up(a0,o), t1=__shfl_up(a1,o);
      if (tid>=o){a0+=t0;a1+=t1;}
    }
    a1 += __shfl(a0,63);
    const float ctot = __shfl(a1,63);
    cexpL[tid]    = d0*__expf(ctot - a0);
    cexpL[tid+64] = d1*__expf(ctot - a1);
    if (tid==0) Pb[wg] = __expf(ctot);
  }
  __syncthreads();
  {
    const int v = tid & 63, r0 = tid >> 6;
    #pragma unroll 4
    for (int k=0;k<32;k++){
      const int s = r0 + k*4;
      Btr[v*STR128 + s] = Bb[(bt0+s)*DSTATE + v];
      Uw[v*STR128 + s]  = f2bf(cexpL[s]*bf2f(xsx[(bt0+s)*DIN + hh*HD + v]));
    }
  }
  __syncthreads();
  const int w = tid>>6, lane = tid&63, q = lane>>4, l16 = lane&15;
  f32x4 acc[4] = {};
  #pragma unroll
  for (int ks=0;ks<4;ks++){
    const bf16x8 af = ldfrag(&Uw[(w*16+l16)*STR128 + ks*32 + q*8]);
    #pragma unroll
    for (int nj=0;nj<4;nj++){
      const bf16x8 bf = ldfrag(&Btr[(nj*16+l16)*STR128 + ks*32 + q*8]);
      acc[nj] = __builtin_amdgcn_mfma_f32_16x16x32_bf16(af, bf, acc[nj], 0,0,0);
    }
  }
  const long sb = (long)wg*4096;   // [wg][p][n]
  #pragma unroll
  for (int nj=0;nj<4;nj++)
    #pragma unroll
    for (int r=0;r<4;r++)
      Sloc[sb + (w*16+q*4+r)*64 + nj*16 + l16] = acc[nj][r];
}

// Parallel combine: Sloc[c] := running; run = P[c]*run + tmp
__global__ __launch_bounds__(64) void scanMid_kernel(float* __restrict__ Sloc, const float* __restrict__ Pb)
{
  const int bh = blockIdx.x;
  const int rr = blockIdx.y;
  const int p  = threadIdx.x;
  float run = 0.f;
  for (int c = 0; c < NCHUNK; ++c) {
    const long base = ((long)(bh*NCHUNK + c))*4096 + rr*64 + p;
    const float Pc = Pb[bh*NCHUNK + c];
    const float tmp = Sloc[base];
    Sloc[base] = run;
    run = run*Pc + tmp;
  }
}

// ---------------- SSD phase C: Y = ((C Bt) o L) U + diag(exp(cum)) (C h0) + D*x ; y out bf16 ----------------
__global__ __launch_bounds__(512) void scanY_kernel(const u16* __restrict__ xsx,
    u16* __restrict__ yg, const u16* __restrict__ Bb, const u16* __restrict__ Cb,
    const float* __restrict__ lab, const float* __restrict__ dtb,
    const float* __restrict__ Sinit, const float* __restrict__ Dp)
{
  __shared__ __align__(16) u16 pool[2*128*STR64];  // Bs | Cs; overlaid by Ms[t][s]
  __shared__ __align__(16) u16 Ut[64*STR128];      // [p][s]
  __shared__ __align__(16) u16 h0t[64*STR64];      // [p][n]
  __shared__ float cumL[128];
  __shared__ float dtL[128];
  u16* Bs = pool;
  u16* Cs = pool + 128*STR64;
  u16* Ms = pool;

  const int wg = blockIdx.x;
  const int c = wg & (NCHUNK-1), bh = wg >> 5, hh = bh & (NH-1), b = bh >> 3;
  const int tid = threadIdx.x;
  const long bt0 = (long)b*SEQ + c*CLEN;

  if (tid < 64) {
    float a0 = lab[(bt0+tid)*NH + hh];
    float a1 = lab[(bt0+64+tid)*NH + hh];
    dtL[tid]    = dtb[(bt0+tid)*NH + hh];
    dtL[tid+64] = dtb[(bt0+64+tid)*NH + hh];
    #pragma unroll
    for (int o=1;o<64;o<<=1){
      const float t0=__shfl_up(a0,o), t1=__shfl_up(a1,o);
      if (tid>=o){a0+=t0;a1+=t1;}
    }
    a1 += __shfl(a0,63);
    cumL[tid]=a0; cumL[tid+64]=a1;
  }
  __syncthreads();
  {
    const int n = tid & 63, r0 = tid >> 6;   // 512 threads: r0 in 0..7
    #pragma unroll 4
    for (int k=0;k<16;k++){
      const int s = r0 + k*8;
      Bs[s*STR64 + n] = Bb[(bt0+s)*DSTATE + n];
      Cs[s*STR64 + n] = Cb[(bt0+s)*DSTATE + n];
      Ut[n*STR128 + s] = f2bf(dtL[s]*bf2f(xsx[(bt0+s)*DIN + hh*HD + n]));
    }
    const int n0 = r0*8;
    const float* hp = Sinit + (long)wg*4096 + n*64 + n0;
    #pragma unroll
    for (int j=0;j<8;j++) h0t[n*STR64 + n0 + j] = f2bf(hp[j]);
  }
  __syncthreads();

  const int w = tid>>6, lane = tid&63, q = lane>>4, l16 = lane&15;
  f32x4 accG[8] = {};
  f32x4 accI[4] = {};
  #pragma unroll
  for (int ks=0;ks<2;ks++){
    const bf16x8 af = ldfrag(&Cs[(w*16+l16)*STR64 + ks*32 + q*8]);
    #pragma unroll
    for (int nj=0;nj<8;nj++)
      accG[nj] = __builtin_amdgcn_mfma_f32_16x16x32_bf16(af, ldfrag(&Bs[(nj*16+l16)*STR64 + ks*32 + q*8]), accG[nj], 0,0,0);
    #pragma unroll
    for (int nj=0;nj<4;nj++)
      accI[nj] = __builtin_amdgcn_mfma_f32_16x16x32_bf16(af, ldfrag(&h0t[(nj*16+l16)*STR64 + ks*32 + q*8]), accI[nj], 0,0,0);
  }
  __syncthreads();
  #pragma unroll
  for (int nj=0;nj<8;nj++){
    const int s = nj*16 + l16;
    #pragma unroll
    for (int r=0;r<4;r++){
      const int t = w*16 + q*4 + r;
      const float v = (s<=t) ? accG[nj][r]*__expf(cumL[t]-cumL[s]) : 0.f;
      Ms[t*STR128 + s] = f2bf(v);
    }
  }
  __syncthreads();
  f32x4 accY[4] = {};
  #pragma unroll
  for (int ks=0;ks<4;ks++){
    const bf16x8 af = ldfrag(&Ms[(w*16+l16)*STR128 + ks*32 + q*8]);
    #pragma unroll
    for (int nj=0;nj<4;nj++)
      accY[nj] = __builtin_amdgcn_mfma_f32_16x16x32_bf16(af, ldfrag(&Ut[(nj*16+l16)*STR128 + ks*32 + q*8]), accY[nj], 0,0,0);
  }
  const float Dv = Dp[hh];
  #pragma unroll
  for (int nj=0;nj<4;nj++){
    const int p = nj*16 + l16;
    #pragma unroll
    for (int r=0;r<4;r++){
      const int t = w*16 + q*4 + r;
      const long a = (bt0+t)*DIN + hh*HD + p;
      const float xv = bf2f(xsx[a]);
      yg[a] = f2bf(accY[nj][r] + __expf(cumL[t])*accI[nj][r] + Dv*xv);
    }
  }
}

// ---------------- y*silu(z) + RMSNorm; bf16 in, bf16 out in place ----------------
__global__ __launch_bounds__(256) void gnorm_kernel(u16* __restrict__ y_io,
    const u16* __restrict__ zb, const float* __restrict__ nw)
{
  const long row = blockIdx.x;
  const int tid = threadIdx.x;
  float g[2];
  #pragma unroll
  for (int q=0;q<2;q++){
    const int cc = tid + q*256;
    const float yv = bf2f(y_io[row*DIN + cc]);
    const float zv = bf2f(zb[row*DIN + cc]);
    g[q] = yv * siluf(zv);
  }
  float ss = g[0]*g[0] + g[1]*g[1];
  #pragma unroll
  for (int o=32;o;o>>=1) ss += __shfl_down(ss, o);
  __shared__ float red[4];
  if ((tid & 63) == 0) red[tid>>6] = ss;
  __syncthreads();
  const float tot = red[0]+red[1]+red[2]+red[3];
  const float scale = rsqrtf(tot * (1.f/512.f) + 1e-5f);
  #pragma unroll
  for (int q=0;q<2;q++){
    const int cc = tid + q*256;
    y_io[row*DIN + cc] = f2bf(g[q] * scale * nw[cc]);
  }
}

// ---------------- LayerNorm; writes h fp32 + hb bf16 ----------------
__global__ __launch_bounds__(256) void ln_kernel(const float* __restrict__ in,
    float* __restrict__ h, u16* __restrict__ hb,
    const float* __restrict__ w, const float* __restrict__ bb)
{
  const int lane = threadIdx.x & 63;
  const int wid  = threadIdx.x >> 6;
  const long row = (long)blockIdx.x * 4 + wid;
  const float* r = in + row*DMODEL;
  float v[4]; float sum = 0.f, sq = 0.f;
  #pragma unroll
  for (int q=0;q<4;q++){ v[q] = r[lane + q*64]; sum += v[q]; sq += v[q]*v[q]; }
  #pragma unroll
  for (int o=32;o;o>>=1){ sum += __shfl_xor(sum,o); sq += __shfl_xor(sq,o); }
  const float mu = sum * (1.f/256.f);
  const float var = sq * (1.f/256.f) - mu*mu;
  const float rs = rsqrtf(var + 1e-5f);
  #pragma unroll
  for (int q=0;q<4;q++){
    const int cc = lane + q*64;
    const float o = (v[q]-mu)*rs*w[cc] + bb[cc];
    h [row*DMODEL + cc] = o;
    hb[row*DMODEL + cc] = f2bf(o);
  }
}

// ---------------- decoder (fp32 output) ----------------
__global__ __launch_bounds__(64) void dec_kernel(const float* __restrict__ h,
    const float* __restrict__ W, const float* __restrict__ bias, float* __restrict__ out)
{
  const int wg = blockIdx.x;
  const int b = wg / 10, o = wg % 10;
  const int lane = threadIdx.x;
  const float* r = h + ((long)b*SEQ + SEQ-1)*DMODEL;
  float s = 0.f;
  #pragma unroll
  for (int q=0;q<4;q++){ const int k = lane + q*64; s += r[k]*W[k*10+o]; }
  #pragma unroll
  for (int o2=32;o2;o2>>=1) s += __shfl_down(s, o2);
  if (lane == 0) out[wg] = s + bias[o];
}

extern "C" void kernel_launch(void* const* d_in, const int* in_sizes, int n_in,
                              void* d_out, int out_size, void* d_ws, size_t ws_size,
                              hipStream_t stream) {
  const float* x        = (const float*)d_in[0];
  const float* enc_w    = (const float*)d_in[1];
  const float* enc_b    = (const float*)d_in[2];
  const float* in_proj  = (const float*)d_in[3];
  const float* conv_w   = (const float*)d_in[4];
  const float* conv_b   = (const float*)d_in[5];
  const float* dt_bias  = (const float*)d_in[6];
  const float* A_log    = (const float*)d_in[7];
  const float* Dp       = (const float*)d_in[8];
  const float* norm_w   = (const float*)d_in[9];
  const float* out_proj = (const float*)d_in[10];
  const float* ln_w     = (const float*)d_in[11];
  const float* ln_b     = (const float*)d_in[12];
  const float* dec_w    = (const float*)d_in[13];
  const float* dec_b    = (const float*)d_in[14];
  float* out = (float*)d_out;

  float* ws = (float*)d_ws;
  u16* WtIn  = (u16*)ws;                       // 2*NPAD*256 shorts = 655360
  u16* WtOut = WtIn + (long)2*NPAD*DMODEL;     // 2*256*512 shorts = 262144
  float* gbase = ws + 327680 + 131072;         // = ws + 458752 floats

  // Per-token fp32-equivalents: h 256 + hb 128 + z 256 + xbc 320 + xsx 256 + yg 256
  //                             + Bb 32 + Cb 32 + dtb 8 + lab 8 = 1552
  int NB = 8;
  while (NB > 1) {
    const long Mb = (long)NB * SEQ;
    const long bytes = (458752L + Mb * 1552L + 4096) * 4;
    if ((size_t)bytes <= ws_size) break;
    NB >>= 1;
  }
  const long Mb = (long)NB * SEQ;

  float* h    = gbase;                    // Mb*256 f
  u16*   hb   = (u16*)(h + Mb*DMODEL);    // Mb*256 u16
  u16*   zbuf = hb + Mb*DMODEL;           // Mb*512 u16
  u16*   xbc  = zbuf + Mb*DIN;            // Mb*640 u16 ; aliased by Sloc/tmp256 (Mb*256 f)
  u16*   xsx  = xbc + Mb*CONVDIM;         // Mb*512 u16
  u16*   yg   = xsx + Mb*DIN;             // Mb*512 u16 (y, then g in place)
  u16*   Bb   = yg + Mb*DIN;              // Mb*64 u16
  u16*   Cb   = Bb + Mb*DSTATE;           // Mb*64 u16
  float* dtb  = (float*)(Cb + Mb*DSTATE); // Mb*8 f
  float* lab  = dtb + Mb*NH;              // Mb*8 f (log dA)
  float* Pb   = lab + Mb*NH;              // <= 2048
  float* Sloc   = (float*)xbc;            // alias: xbc dead after conv
  float* tmp256 = (float*)xbc;            // alias: Sloc dead after scanY

  cvt_inw <<<dim3(2*NPAD),   dim3(256), 0, stream>>>(in_proj,  WtIn);
  cvt_outw<<<dim3(2*DMODEL), dim3(256), 0, stream>>>(out_proj, WtOut);

  const int ngroups = B_SZ / NB;
  for (int g = 0; g < ngroups; ++g) {
    const float* xg = x + (long)g*NB*SEQ*64;

    enc_kernel<<<dim3((int)(Mb/32)), dim3(256), 0, stream>>>(xg, enc_w, enc_b, h, hb);

    for (int l = 0; l < 2; ++l) {
      inproj_mfma<<<dim3((int)(Mb/128), NPAD/128), dim3(256), 0, stream>>>(
          hb, WtIn + (long)l*NPAD*DMODEL, zbuf, xbc, dtb, lab,
          dt_bias + l*NH, A_log + l*NH);
      conv_kernel<<<dim3((int)(Mb*20/256)), dim3(256), 0, stream>>>(
          xbc, conv_w + (long)l*CONVDIM*4, conv_b + (long)l*CONVDIM, xsx, Bb, Cb);
      scanS_kernel<<<dim3(NB*8*NCHUNK), dim3(256), 0, stream>>>(xsx, Bb, lab, dtb, Sloc, Pb);
      scanMid_kernel<<<dim3(NB*8, 64), dim3(64), 0, stream>>>(Sloc, Pb);
      scanY_kernel<<<dim3(NB*8*NCHUNK), dim3(512), 0, stream>>>(xsx, yg, Bb, Cb, lab, dtb, Sloc, Dp + l*NH);
      gnorm_kernel<<<dim3((int)Mb), dim3(256), 0, stream>>>(yg, zbuf, norm_w + (long)l*DIN);
      outproj_mfma<<<dim3((int)(Mb/128), 2), dim3(256), 0, stream>>>(
          yg, WtOut + (long)l*DMODEL*DIN, h, tmp256);
      ln_kernel<<<dim3((int)(Mb/4)), dim3(256), 0, stream>>>(tmp256, h, hb, ln_w + l*DMODEL, ln_b + l*DMODEL);
    }

    dec_kernel<<<dim3(NB*10), dim3(64), 0, stream>>>(h, dec_w, dec_b, out + (long)g*NB*10);
  }
}

// Round 10
// 548.134 us; speedup vs baseline: 8.0456x; 1.1182x over previous
//
#include <hip/hip_runtime.h>
#include <hip/hip_bf16.h>
#include <math.h>

// ---- model constants ----
#define B_SZ    8
#define SEQ     4096
#define DMODEL  256
#define DIN     512     // d_inner
#define DSTATE  64
#define NH      8
#define HD      64
#define CONVDIM 640
#define DPROJ   1160
#define NPAD    1280    // DPROJ padded to 10*128
#define NCHUNK  32      // scan chunks per (b,h)
#define CLEN    128     // SEQ / NCHUNK
#define STR64   68      // LDS row stride (shorts) for K=64 tiles
#define STR128  132     // LDS row stride (shorts) for K=128 tiles

typedef unsigned long long u64;
typedef unsigned int u32;
typedef unsigned short u16;
typedef __attribute__((ext_vector_type(8))) short bf16x8;
typedef __attribute__((ext_vector_type(4))) float f32x4;

__device__ __forceinline__ float siluf(float v){ return v / (1.f + expf(-v)); }
__device__ __forceinline__ u16 f2bf(float f){ __hip_bfloat16 h = __float2bfloat16(f); return *(u16*)&h; }
__device__ __forceinline__ float bf2f(u16 u){ union{u32 i; float f;} t; t.i = ((u32)u)<<16; return t.f; }
__device__ __forceinline__ bf16x8 ldfrag(const u16* base){
  union { u64 u[2]; bf16x8 v; } t;
  const u64* p = (const u64*)base;
  t.u[0] = p[0]; t.u[1] = p[1];
  return t.v;
}

// ---------------- weight conversion (once per launch) ----------------
__global__ __launch_bounds__(256) void cvt_inw(const float* __restrict__ W, u16* __restrict__ Wt)
{
  const int blk = blockIdx.x;
  const int l = blk / NPAD, n = blk % NPAD;
  const int k = threadIdx.x;
  float v = 0.f;
  if (n < DPROJ) v = W[((long)l*DMODEL + k)*DPROJ + n];
  Wt[((long)l*NPAD + n)*DMODEL + k] = f2bf(v);
}

__global__ __launch_bounds__(256) void cvt_outw(const float* __restrict__ W, u16* __restrict__ Wt)
{
  const int blk = blockIdx.x;
  const int l = blk / DMODEL, n = blk % DMODEL;
  #pragma unroll
  for (int q = 0; q < 2; ++q) {
    const int k = threadIdx.x + q*256;
    const float v = W[((long)l*DIN + k)*DMODEL + n];
    Wt[((long)l*DMODEL + n)*DIN + k] = f2bf(v);
  }
}

// ---------------- encoder GEMM; writes h fp32 + hb bf16 ----------------
__global__ __launch_bounds__(256) void enc_kernel(const float* __restrict__ x,
    const float* __restrict__ W, const float* __restrict__ bias,
    float* __restrict__ h, u16* __restrict__ hb)
{
  __shared__ float xl[32*64];
  const int tid = threadIdx.x;
  const long t0 = (long)blockIdx.x * 32;
  for (int i = tid; i < 32*64; i += 256) xl[i] = x[t0*64 + i];
  __syncthreads();
  float acc[32];
  const float bv = bias[tid];
  #pragma unroll
  for (int tok = 0; tok < 32; ++tok) acc[tok] = bv;
  for (int k = 0; k < 64; ++k) {
    const float wv = W[k*DMODEL + tid];
    #pragma unroll
    for (int tok = 0; tok < 32; ++tok) acc[tok] += xl[tok*64 + k] * wv;
  }
  #pragma unroll
  for (int tok = 0; tok < 32; ++tok) {
    h [(t0 + tok)*DMODEL + tid] = acc[tok];
    hb[(t0 + tok)*DMODEL + tid] = f2bf(acc[tok]);
  }
}

// ---------------- in_proj MFMA GEMM 128x128 tile, BK=32; LDS-bounce coalesced epilogue ----------------
__global__ __launch_bounds__(256) void inproj_mfma(const u16* __restrict__ hb,
    const u16* __restrict__ Wt, u16* __restrict__ zbuf, u16* __restrict__ xbc,
    float* __restrict__ dtb, float* __restrict__ lab,
    const float* __restrict__ dt_bias, const float* __restrict__ A_log)
{
  __shared__ __align__(16) u16 pool[128*36*2];   // staging Asl|Bsl; epilogue bounce aliases it
  u16* Asl = pool;
  u16* Bsl = pool + 128*36;
  u16* Ep  = pool;                               // [64][136] u16 per mi-half
  const int tid = threadIdx.x;
  const long m0 = (long)blockIdx.x * 128;
  const int n0 = blockIdx.y * 128;
  const int w = tid >> 6, lane = tid & 63;
  const int q = lane >> 4, l16 = lane & 15;
  const int srow = tid >> 1, sseg = tid & 1;   // 2 lanes/row, 16 shorts (32 B) each
  f32x4 acc[2][8] = {{{0.f,0.f,0.f,0.f}}};
  for (int k0 = 0; k0 < DMODEL; k0 += 32) {
    {
      const u64* s = (const u64*)(hb + (m0 + srow)*DMODEL + k0 + sseg*16);
      u64 a=s[0], b=s[1], c=s[2], d=s[3];
      u64* dst = (u64*)(&Asl[srow*36 + sseg*16]);
      dst[0]=a; dst[1]=b; dst[2]=c; dst[3]=d;
    }
    {
      const u64* s = (const u64*)(Wt + (long)(n0 + srow)*DMODEL + k0 + sseg*16);
      u64 a=s[0], b=s[1], c=s[2], d=s[3];
      u64* dst = (u64*)(&Bsl[srow*36 + sseg*16]);
      dst[0]=a; dst[1]=b; dst[2]=c; dst[3]=d;
    }
    __syncthreads();
    bf16x8 af[2], bfr[8];
    #pragma unroll
    for (int mi=0;mi<2;mi++) af[mi] = ldfrag(&Asl[(w*32 + mi*16 + l16)*36 + q*8]);
    #pragma unroll
    for (int nj=0;nj<8;nj++) bfr[nj] = ldfrag(&Bsl[(nj*16 + l16)*36 + q*8]);
    #pragma unroll
    for (int mi=0;mi<2;mi++)
      #pragma unroll
      for (int nj=0;nj<8;nj++)
        acc[mi][nj] = __builtin_amdgcn_mfma_f32_16x16x32_bf16(af[mi], bfr[nj], acc[mi][nj], 0,0,0);
    __syncthreads();
  }
  if (n0 < DIN + CONVDIM) {
    // bounce each 64-row half through LDS, then full-line stores (4 thr/row x 32 shorts = 128)
    #pragma unroll
    for (int mi=0;mi<2;mi++){
      #pragma unroll
      for (int nj=0;nj<8;nj++){
        const int col = nj*16 + l16;
        #pragma unroll
        for (int r=0;r<4;r++){
          const int er = w*16 + q*4 + r;
          Ep[er*136 + col] = f2bf(acc[mi][nj][r]);
        }
      }
      __syncthreads();
      {
        const int er2 = tid >> 2, seg = tid & 3;
        const long grow = m0 + (er2>>4)*32 + mi*16 + (er2&15);
        const u64* s = (const u64*)(Ep + er2*136 + seg*32);
        u64 v0=s[0], v1=s[1], v2=s[2], v3=s[3], v4=s[4], v5=s[5], v6=s[6], v7=s[7];
        u64* dptr;
        if (n0 < DIN) dptr = (u64*)(zbuf + grow*DIN + n0 + seg*32);
        else          dptr = (u64*)(xbc + grow*CONVDIM + (n0 - DIN) + seg*32);
        dptr[0]=v0; dptr[1]=v1; dptr[2]=v2; dptr[3]=v3;
        dptr[4]=v4; dptr[5]=v5; dptr[6]=v6; dptr[7]=v7;
      }
      __syncthreads();
    }
  } else {
    // dt tile: only cols 1152..1159 valid
    #pragma unroll
    for (int mi=0;mi<2;mi++){
      #pragma unroll
      for (int nj=0;nj<8;nj++){
        const int col = n0 + nj*16 + l16;
        if (col < DPROJ) {
          const int hh = col - (DIN + CONVDIM);
          #pragma unroll
          for (int r=0;r<4;r++){
            const long row = m0 + w*32 + mi*16 + q*4 + r;
            const float dv = acc[mi][nj][r] + dt_bias[hh];
            const float sp = dv > 20.f ? dv : log1pf(expf(dv));
            dtb[row*NH + hh] = sp;
            lab[row*NH + hh] = sp * (-expf(A_log[hh]));   // log dA
          }
        }
      }
    }
  }
}

// ---------------- out_proj MFMA GEMM 128x128 tile + residual ----------------
__global__ __launch_bounds__(256) void outproj_mfma(const u16* __restrict__ gb,
    const u16* __restrict__ Wt, const float* __restrict__ resid, float* __restrict__ outb)
{
  __shared__ u16 Asl[128*36];
  __shared__ u16 Bsl[128*36];
  const int tid = threadIdx.x;
  const long m0 = (long)blockIdx.x * 128;
  const int n0 = blockIdx.y * 128;
  const int w = tid >> 6, lane = tid & 63;
  const int q = lane >> 4, l16 = lane & 15;
  const int srow = tid >> 1, sseg = tid & 1;
  f32x4 acc[2][8] = {{{0.f,0.f,0.f,0.f}}};
  for (int k0 = 0; k0 < DIN; k0 += 32) {
    {
      const u64* s = (const u64*)(gb + (m0 + srow)*DIN + k0 + sseg*16);
      u64 a=s[0], b=s[1], c=s[2], d=s[3];
      u64* dst = (u64*)(&Asl[srow*36 + sseg*16]);
      dst[0]=a; dst[1]=b; dst[2]=c; dst[3]=d;
    }
    {
      const u64* s = (const u64*)(Wt + (long)(n0 + srow)*DIN + k0 + sseg*16);
      u64 a=s[0], b=s[1], c=s[2], d=s[3];
      u64* dst = (u64*)(&Bsl[srow*36 + sseg*16]);
      dst[0]=a; dst[1]=b; dst[2]=c; dst[3]=d;
    }
    __syncthreads();
    bf16x8 af[2], bfr[8];
    #pragma unroll
    for (int mi=0;mi<2;mi++) af[mi] = ldfrag(&Asl[(w*32 + mi*16 + l16)*36 + q*8]);
    #pragma unroll
    for (int nj=0;nj<8;nj++) bfr[nj] = ldfrag(&Bsl[(nj*16 + l16)*36 + q*8]);
    #pragma unroll
    for (int mi=0;mi<2;mi++)
      #pragma unroll
      for (int nj=0;nj<8;nj++)
        acc[mi][nj] = __builtin_amdgcn_mfma_f32_16x16x32_bf16(af[mi], bfr[nj], acc[mi][nj], 0,0,0);
    __syncthreads();
  }
  #pragma unroll
  for (int mi=0;mi<2;mi++){
    #pragma unroll
    for (int nj=0;nj<8;nj++){
      const int col = n0 + nj*16 + l16;
      #pragma unroll
      for (int r=0;r<4;r++){
        const long row = m0 + w*32 + mi*16 + q*4 + r;
        outb[row*DMODEL + col] = acc[mi][nj][r] + resid[row*DMODEL + col];
      }
    }
  }
}

// ---------------- depthwise causal conv + SiLU: strip kernel ----------------
__global__ __launch_bounds__(256) void conv_kernel(const u16* __restrict__ xbc,
    const float* __restrict__ cw, const float* __restrict__ cb,
    u16* __restrict__ xsx, u16* __restrict__ Bb, u16* __restrict__ Cb)
{
  const long idx = (long)blockIdx.x * 256 + threadIdx.x;   // Mb*20 threads
  const int c4 = (int)(idx % 160) * 4;
  const long bt0 = (idx / 160) * 8;          // strip start (strips never cross batch)
  const int tseq = (int)(bt0 & (SEQ-1));
  const float4 b4 = *(const float4*)(cb + c4);
  const float4 w0v = *(const float4*)(cw + (c4+0)*4);
  const float4 w1v = *(const float4*)(cw + (c4+1)*4);
  const float4 w2v = *(const float4*)(cw + (c4+2)*4);
  const float4 w3v = *(const float4*)(cw + (c4+3)*4);
  const float W0[4] = {w0v.x,w0v.y,w0v.z,w0v.w};
  const float W1[4] = {w1v.x,w1v.y,w1v.z,w1v.w};
  const float W2[4] = {w2v.x,w2v.y,w2v.z,w2v.w};
  const float W3[4] = {w3v.x,w3v.y,w3v.z,w3v.w};
  float i0[11], i1[11], i2[11], i3[11];
  #pragma unroll
  for (int k = 0; k < 11; ++k) {
    u64 v = 0;
    if (tseq - 3 + k >= 0) v = *(const u64*)(xbc + (bt0 - 3 + k)*CONVDIM + c4);
    i0[k]=bf2f((u16)v); i1[k]=bf2f((u16)(v>>16)); i2[k]=bf2f((u16)(v>>32)); i3[k]=bf2f((u16)(v>>48));
  }
  u16* dst; long base; int stride;
  if (c4 < DIN)              { dst = xsx; base = bt0*DIN + c4;              stride = DIN; }
  else if (c4 < DIN+DSTATE)  { dst = Bb;  base = bt0*DSTATE + (c4-DIN);     stride = DSTATE; }
  else                       { dst = Cb;  base = bt0*DSTATE + (c4-DIN-DSTATE); stride = DSTATE; }
  #pragma unroll
  for (int j = 0; j < 8; ++j) {
    float a0=b4.x, a1=b4.y, a2=b4.z, a3=b4.w;
    #pragma unroll
    for (int k = 0; k < 4; ++k) {
      a0 += W0[k]*i0[j+k]; a1 += W1[k]*i1[j+k];
      a2 += W2[k]*i2[j+k]; a3 += W3[k]*i3[j+k];
    }
    a0=siluf(a0); a1=siluf(a1); a2=siluf(a2); a3=siluf(a3);
    const u64 r = (u64)f2bf(a0) | ((u64)f2bf(a1)<<16) | ((u64)f2bf(a2)<<32) | ((u64)f2bf(a3)<<48);
    *(u64*)(dst + base + (long)j*stride) = r;
  }
}

// ---------------- SSD phase A: per chunk-head local state via MFMA ----------------
__global__ __launch_bounds__(256) void scanS_kernel(const u16* __restrict__ xsx,
    const u16* __restrict__ Bb, const float* __restrict__ lab, const float* __restrict__ dtb,
    float* __restrict__ Sloc, float* __restrict__ Pb)
{
  __shared__ __align__(16) u16 Btr[64*STR128];   // [n][s]
  __shared__ __align__(16) u16 Uw[64*STR128];    // [p][s]
  __shared__ float cexpL[128];
  const int wg = blockIdx.x;
  const int c = wg & (NCHUNK-1), bh = wg >> 5, hh = bh & (NH-1), b = bh >> 3;
  const int tid = threadIdx.x;
  const long bt0 = (long)b*SEQ + c*CLEN;
  if (tid < 64) {   // wave 0: inclusive prefix of log dA over 128 steps
    float a0 = lab[(bt0+tid)*NH + hh];
    float a1 = lab[(bt0+64+tid)*NH + hh];
    const float d0 = dtb[(bt0+tid)*NH + hh];
    const float d1 = dtb[(bt0+64+tid)*NH + hh];
    #pragma unroll
    for (int o=1;o<64;o<<=1){
      const float t0=__shfl_up(a0,o), t1=__shfl_up(a1,o);
      if (tid>=o){a0+=t0;a1+=t1;}
    }
    a1 += __shfl(a0,63);
    const float ctot = __shfl(a1,63);
    cexpL[tid]    = d0*__expf(ctot - a0);
    cexpL[tid+64] = d1*__expf(ctot - a1);
    if (tid==0) Pb[wg] = __expf(ctot);
  }
  __syncthreads();
  {
    const int v = tid & 63, r0 = tid >> 6;
    #pragma unroll 4
    for (int k=0;k<32;k++){
      const int s = r0 + k*4;
      Btr[v*STR128 + s] = Bb[(bt0+s)*DSTATE + v];
      Uw[v*STR128 + s]  = f2bf(cexpL[s]*bf2f(xsx[(bt0+s)*DIN + hh*HD + v]));
    }
  }
  __syncthreads();
  const int w = tid>>6, lane = tid&63, q = lane>>4, l16 = lane&15;
  f32x4 acc[4] = {};
  #pragma unroll
  for (int ks=0;ks<4;ks++){
    const bf16x8 af = ldfrag(&Uw[(w*16+l16)*STR128 + ks*32 + q*8]);
    #pragma unroll
    for (int nj=0;nj<4;nj++){
      const bf16x8 bf = ldfrag(&Btr[(nj*16+l16)*STR128 + ks*32 + q*8]);
      acc[nj] = __builtin_amdgcn_mfma_f32_16x16x32_bf16(af, bf, acc[nj], 0,0,0);
    }
  }
  const long sb = (long)wg*4096;   // [wg][p][n]
  #pragma unroll
  for (int nj=0;nj<4;nj++)
    #pragma unroll
    for (int r=0;r<4;r++)
      Sloc[sb + (w*16+q*4+r)*64 + nj*16 + l16] = acc[nj][r];
}

// Parallel combine: Sloc[c] := running; run = P[c]*run + tmp
__global__ __launch_bounds__(64) void scanMid_kernel(float* __restrict__ Sloc, const float* __restrict__ Pb)
{
  const int bh = blockIdx.x;
  const int rr = blockIdx.y;
  const int p  = threadIdx.x;
  float run = 0.f;
  for (int c = 0; c < NCHUNK; ++c) {
    const long base = ((long)(bh*NCHUNK + c))*4096 + rr*64 + p;
    const float Pc = Pb[bh*NCHUNK + c];
    const float tmp = Sloc[base];
    Sloc[base] = run;
    run = run*Pc + tmp;
  }
}

// ---------------- SSD phase C: Y = ((C Bt) o L) U + diag(exp(cum)) (C h0) + D*x ; coalesced y out ----------------
__global__ __launch_bounds__(512) void scanY_kernel(const u16* __restrict__ xsx,
    u16* __restrict__ yg, const u16* __restrict__ Bb, const u16* __restrict__ Cb,
    const float* __restrict__ lab, const float* __restrict__ dtb,
    const float* __restrict__ Sinit, const float* __restrict__ Dp)
{
  __shared__ __align__(16) u16 pool[2*128*STR64];  // Bs | Cs; overlaid by Ms[t][s]; then by y-bounce
  __shared__ __align__(16) u16 Ut[64*STR128];      // [p][s]
  __shared__ __align__(16) u16 h0t[64*STR64];      // [p][n]
  __shared__ float cumL[128];
  __shared__ float dtL[128];
  u16* Bs = pool;
  u16* Cs = pool + 128*STR64;
  u16* Ms = pool;

  const int wg = blockIdx.x;
  const int c = wg & (NCHUNK-1), bh = wg >> 5, hh = bh & (NH-1), b = bh >> 3;
  const int tid = threadIdx.x;
  const long bt0 = (long)b*SEQ + c*CLEN;

  if (tid < 64) {
    float a0 = lab[(bt0+tid)*NH + hh];
    float a1 = lab[(bt0+64+tid)*NH + hh];
    dtL[tid]    = dtb[(bt0+tid)*NH + hh];
    dtL[tid+64] = dtb[(bt0+64+tid)*NH + hh];
    #pragma unroll
    for (int o=1;o<64;o<<=1){
      const float t0=__shfl_up(a0,o), t1=__shfl_up(a1,o);
      if (tid>=o){a0+=t0;a1+=t1;}
    }
    a1 += __shfl(a0,63);
    cumL[tid]=a0; cumL[tid+64]=a1;
  }
  __syncthreads();
  {
    const int n = tid & 63, r0 = tid >> 6;   // 512 threads: r0 in 0..7
    #pragma unroll 4
    for (int k=0;k<16;k++){
      const int s = r0 + k*8;
      Bs[s*STR64 + n] = Bb[(bt0+s)*DSTATE + n];
      Cs[s*STR64 + n] = Cb[(bt0+s)*DSTATE + n];
      Ut[n*STR128 + s] = f2bf(dtL[s]*bf2f(xsx[(bt0+s)*DIN + hh*HD + n]));
    }
    const int n0 = r0*8;
    const float* hp = Sinit + (long)wg*4096 + n*64 + n0;
    #pragma unroll
    for (int j=0;j<8;j++) h0t[n*STR64 + n0 + j] = f2bf(hp[j]);
  }
  __syncthreads();

  const int w = tid>>6, lane = tid&63, q = lane>>4, l16 = lane&15;
  f32x4 accG[8] = {};
  f32x4 accI[4] = {};
  #pragma unroll
  for (int ks=0;ks<2;ks++){
    const bf16x8 af = ldfrag(&Cs[(w*16+l16)*STR64 + ks*32 + q*8]);
    #pragma unroll
    for (int nj=0;nj<8;nj++)
      accG[nj] = __builtin_amdgcn_mfma_f32_16x16x32_bf16(af, ldfrag(&Bs[(nj*16+l16)*STR64 + ks*32 + q*8]), accG[nj], 0,0,0);
    #pragma unroll
    for (int nj=0;nj<4;nj++)
      accI[nj] = __builtin_amdgcn_mfma_f32_16x16x32_bf16(af, ldfrag(&h0t[(nj*16+l16)*STR64 + ks*32 + q*8]), accI[nj], 0,0,0);
  }
  __syncthreads();
  #pragma unroll
  for (int nj=0;nj<8;nj++){
    const int s = nj*16 + l16;
    #pragma unroll
    for (int r=0;r<4;r++){
      const int t = w*16 + q*4 + r;
      const float v = (s<=t) ? accG[nj][r]*__expf(cumL[t]-cumL[s]) : 0.f;
      Ms[t*STR128 + s] = f2bf(v);
    }
  }
  __syncthreads();
  f32x4 accY[4] = {};
  #pragma unroll
  for (int ks=0;ks<4;ks++){
    const bf16x8 af = ldfrag(&Ms[(w*16+l16)*STR128 + ks*32 + q*8]);
    #pragma unroll
    for (int nj=0;nj<4;nj++)
      accY[nj] = __builtin_amdgcn_mfma_f32_16x16x32_bf16(af, ldfrag(&Ut[(nj*16+l16)*STR128 + ks*32 + q*8]), accY[nj], 0,0,0);
  }
  const float Dv = Dp[hh];
  __syncthreads();   // Ms reads done; reuse pool as y-bounce [128][68]
  #pragma unroll
  for (int nj=0;nj<4;nj++){
    const int p = nj*16 + l16;
    #pragma unroll
    for (int r=0;r<4;r++){
      const int t = w*16 + q*4 + r;
      const float xv = bf2f(xsx[(bt0+t)*DIN + hh*HD + p]);
      pool[t*STR64 + p] = f2bf(accY[nj][r] + __expf(cumL[t])*accI[nj][r] + Dv*xv);
    }
  }
  __syncthreads();
  {
    const int row = tid >> 2, seg = tid & 3;
    const u64* s = (const u64*)(pool + row*STR64 + seg*16);
    u64 a=s[0], b2=s[1], c2=s[2], d=s[3];
    u64* dptr = (u64*)(yg + (bt0+row)*DIN + hh*HD + seg*16);
    dptr[0]=a; dptr[1]=b2; dptr[2]=c2; dptr[3]=d;
  }
}

// ---------------- y*silu(z) + RMSNorm; bf16 in, bf16 out in place ----------------
__global__ __launch_bounds__(256) void gnorm_kernel(u16* __restrict__ y_io,
    const u16* __restrict__ zb, const float* __restrict__ nw)
{
  const long row = blockIdx.x;
  const int tid = threadIdx.x;
  float g[2];
  #pragma unroll
  for (int q=0;q<2;q++){
    const int cc = tid + q*256;
    const float yv = bf2f(y_io[row*DIN + cc]);
    const float zv = bf2f(zb[row*DIN + cc]);
    g[q] = yv * siluf(zv);
  }
  float ss = g[0]*g[0] + g[1]*g[1];
  #pragma unroll
  for (int o=32;o;o>>=1) ss += __shfl_down(ss, o);
  __shared__ float red[4];
  if ((tid & 63) == 0) red[tid>>6] = ss;
  __syncthreads();
  const float tot = red[0]+red[1]+red[2]+red[3];
  const float scale = rsqrtf(tot * (1.f/512.f) + 1e-5f);
  #pragma unroll
  for (int q=0;q<2;q++){
    const int cc = tid + q*256;
    y_io[row*DIN + cc] = f2bf(g[q] * scale * nw[cc]);
  }
}

// ---------------- LayerNorm; writes h fp32 + hb bf16 ----------------
__global__ __launch_bounds__(256) void ln_kernel(const float* __restrict__ in,
    float* __restrict__ h, u16* __restrict__ hb,
    const float* __restrict__ w, const float* __restrict__ bb)
{
  const int lane = threadIdx.x & 63;
  const int wid  = threadIdx.x >> 6;
  const long row = (long)blockIdx.x * 4 + wid;
  const float* r = in + row*DMODEL;
  float v[4]; float sum = 0.f, sq = 0.f;
  #pragma unroll
  for (int q=0;q<4;q++){ v[q] = r[lane + q*64]; sum += v[q]; sq += v[q]*v[q]; }
  #pragma unroll
  for (int o=32;o;o>>=1){ sum += __shfl_xor(sum,o); sq += __shfl_xor(sq,o); }
  const float mu = sum * (1.f/256.f);
  const float var = sq * (1.f/256.f) - mu*mu;
  const float rs = rsqrtf(var + 1e-5f);
  #pragma unroll
  for (int q=0;q<4;q++){
    const int cc = lane + q*64;
    const float o = (v[q]-mu)*rs*w[cc] + bb[cc];
    h [row*DMODEL + cc] = o;
    hb[row*DMODEL + cc] = f2bf(o);
  }
}

// ---------------- decoder (fp32 output) ----------------
__global__ __launch_bounds__(64) void dec_kernel(const float* __restrict__ h,
    const float* __restrict__ W, const float* __restrict__ bias, float* __restrict__ out)
{
  const int wg = blockIdx.x;
  const int b = wg / 10, o = wg % 10;
  const int lane = threadIdx.x;
  const float* r = h + ((long)b*SEQ + SEQ-1)*DMODEL;
  float s = 0.f;
  #pragma unroll
  for (int q=0;q<4;q++){ const int k = lane + q*64; s += r[k]*W[k*10+o]; }
  #pragma unroll
  for (int o2=32;o2;o2>>=1) s += __shfl_down(s, o2);
  if (lane == 0) out[wg] = s + bias[o];
}

extern "C" void kernel_launch(void* const* d_in, const int* in_sizes, int n_in,
                              void* d_out, int out_size, void* d_ws, size_t ws_size,
                              hipStream_t stream) {
  const float* x        = (const float*)d_in[0];
  const float* enc_w    = (const float*)d_in[1];
  const float* enc_b    = (const float*)d_in[2];
  const float* in_proj  = (const float*)d_in[3];
  const float* conv_w   = (const float*)d_in[4];
  const float* conv_b   = (const float*)d_in[5];
  const float* dt_bias  = (const float*)d_in[6];
  const float* A_log    = (const float*)d_in[7];
  const float* Dp       = (const float*)d_in[8];
  const float* norm_w   = (const float*)d_in[9];
  const float* out_proj = (const float*)d_in[10];
  const float* ln_w     = (const float*)d_in[11];
  const float* ln_b     = (const float*)d_in[12];
  const float* dec_w    = (const float*)d_in[13];
  const float* dec_b    = (const float*)d_in[14];
  float* out = (float*)d_out;

  float* ws = (float*)d_ws;
  u16* WtIn  = (u16*)ws;                       // 2*NPAD*256 shorts = 655360
  u16* WtOut = WtIn + (long)2*NPAD*DMODEL;     // 2*256*512 shorts = 262144
  float* gbase = ws + 327680 + 131072;         // = ws + 458752 floats

  // Per-token fp32-equivalents: h 256 + hb 128 + z 256 + xbc 320 + xsx 256 + yg 256
  //                             + Bb 32 + Cb 32 + dtb 8 + lab 8 = 1552
  int NB = 8;
  while (NB > 1) {
    const long Mb = (long)NB * SEQ;
    const long bytes = (458752L + Mb * 1552L + 4096) * 4;
    if ((size_t)bytes <= ws_size) break;
    NB >>= 1;
  }
  const long Mb = (long)NB * SEQ;

  float* h    = gbase;                    // Mb*256 f
  u16*   hb   = (u16*)(h + Mb*DMODEL);    // Mb*256 u16
  u16*   zbuf = hb + Mb*DMODEL;           // Mb*512 u16
  u16*   xbc  = zbuf + Mb*DIN;            // Mb*640 u16 ; aliased by Sloc/tmp256 (Mb*256 f)
  u16*   xsx  = xbc + Mb*CONVDIM;         // Mb*512 u16
  u16*   yg   = xsx + Mb*DIN;             // Mb*512 u16 (y, then g in place)
  u16*   Bb   = yg + Mb*DIN;              // Mb*64 u16
  u16*   Cb   = Bb + Mb*DSTATE;           // Mb*64 u16
  float* dtb  = (float*)(Cb + Mb*DSTATE); // Mb*8 f
  float* lab  = dtb + Mb*NH;              // Mb*8 f (log dA)
  float* Pb   = lab + Mb*NH;              // <= 2048
  float* Sloc   = (float*)xbc;            // alias: xbc dead after conv
  float* tmp256 = (float*)xbc;            // alias: Sloc dead after scanY

  cvt_inw <<<dim3(2*NPAD),   dim3(256), 0, stream>>>(in_proj,  WtIn);
  cvt_outw<<<dim3(2*DMODEL), dim3(256), 0, stream>>>(out_proj, WtOut);

  const int ngroups = B_SZ / NB;
  for (int g = 0; g < ngroups; ++g) {
    const float* xg = x + (long)g*NB*SEQ*64;

    enc_kernel<<<dim3((int)(Mb/32)), dim3(256), 0, stream>>>(xg, enc_w, enc_b, h, hb);

    for (int l = 0; l < 2; ++l) {
      inproj_mfma<<<dim3((int)(Mb/128), NPAD/128), dim3(256), 0, stream>>>(
          hb, WtIn + (long)l*NPAD*DMODEL, zbuf, xbc, dtb, lab,
          dt_bias + l*NH, A_log + l*NH);
      conv_kernel<<<dim3((int)(Mb*20/256)), dim3(256), 0, stream>>>(
          xbc, conv_w + (long)l*CONVDIM*4, conv_b + (long)l*CONVDIM, xsx, Bb, Cb);
      scanS_kernel<<<dim3(NB*8*NCHUNK), dim3(256), 0, stream>>>(xsx, Bb, lab, dtb, Sloc, Pb);
      scanMid_kernel<<<dim3(NB*8, 64), dim3(64), 0, stream>>>(Sloc, Pb);
      scanY_kernel<<<dim3(NB*8*NCHUNK), dim3(512), 0, stream>>>(xsx, yg, Bb, Cb, lab, dtb, Sloc, Dp + l*NH);
      gnorm_kernel<<<dim3((int)Mb), dim3(256), 0, stream>>>(yg, zbuf, norm_w + (long)l*DIN);
      outproj_mfma<<<dim3((int)(Mb/128), 2), dim3(256), 0, stream>>>(
          yg, WtOut + (long)l*DMODEL*DIN, h, tmp256);
      ln_kernel<<<dim3((int)(Mb/4)), dim3(256), 0, stream>>>(tmp256, h, hb, ln_w + l*DMODEL, ln_b + l*DMODEL);
    }

    dec_kernel<<<dim3(NB*10), dim3(64), 0, stream>>>(h, dec_w, dec_b, out + (long)g*NB*10);
  }
}